// Round 14
// baseline (308.127 us; speedup 1.0000x reference)
//
#include <hip/hip_runtime.h>
#include <math.h>

#define BB 4
#define NC 4096
#define NT 1024
#define NN (NC + NT)      // 5120
#define NODES (BB * NN)   // 20480
#define DD 64
#define KNN 10
#define NBLK 6
#define BIGF 3.0e38f
#define LM 5              // per-lane kept candidates (union covers global top-10, p_fail ~ 2e-7)

typedef __attribute__((ext_vector_type(8))) short short8;
typedef __attribute__((ext_vector_type(4))) float f32x4;
typedef __attribute__((ext_vector_type(4))) int int4v;

__device__ __forceinline__ unsigned short f2bf(float f) {
    unsigned int u = __float_as_uint(f);
    unsigned int r = (u + 0x7fffu + ((u >> 16) & 1u)) >> 16;
    return (unsigned short)r;
}
__device__ __forceinline__ float bf2f(unsigned short h) {
    return __uint_as_float(((unsigned int)h) << 16);
}

__device__ __forceinline__ float gelu_f(float x) {
    const float c0 = 0.7978845608028654f;
    float x3 = x * x * x;
    float z2 = 2.0f * c0 * (x + 0.044715f * x3);
    float e = __expf(z2);
    float r = __builtin_amdgcn_rcpf(1.0f + e);
    return x - x * r;
}

__device__ __forceinline__ float wave_sum(float v) {
#pragma unroll
    for (int off = 32; off > 0; off >>= 1) v += __shfl_xor(v, off, 64);
    return v;
}

__device__ __forceinline__ f32x4 mfma_bf16(short8 a, short8 b, f32x4 c) {
    asm("v_mfma_f32_16x16x32_bf16 %0, %1, %2, %0" : "+v"(c) : "v"(a), "v"(b));
    return c;
}

// perm(col) = (col&15)*8 + (col>>4); invperm(cp) = ((cp&7)<<4) | (cp>>3)

// ---------------- weight convert + masked s4 pack ----------------
__global__ __launch_bounds__(256) void k_convw(
    const float* __restrict__ Wm0, const float* __restrict__ Wm1,
    const float* __restrict__ Wu0, const float* __restrict__ Wu1,
    const float* __restrict__ bm0,
    const float* __restrict__ eW0, const float* __restrict__ eW1,
    const float* __restrict__ eW2,
    const float* __restrict__ hW0, const float* __restrict__ hW1,
    const float* __restrict__ sctx, const int* __restrict__ valid_lens,
    unsigned short* __restrict__ wtm0, unsigned short* __restrict__ wtm1p,
    unsigned short* __restrict__ wtu0, unsigned short* __restrict__ wtu1,
    float* __restrict__ wdp, float* __restrict__ bm0p,
    unsigned short* __restrict__ wte0, unsigned short* __restrict__ wte1,
    unsigned short* __restrict__ wte2,
    unsigned short* __restrict__ wth0, unsigned short* __restrict__ wth1,
    float4* __restrict__ s4)
{
    int t = blockIdx.x * 256 + threadIdx.x;
    if (t < 49152) {                 // wtm0 [6][128][64]
        int i = t / 8192, r = t % 8192, n = r / 64, k = r % 64;
        wtm0[t] = f2bf(Wm0[(i * 65 + k) * 128 + n]);
    } else if (t < 98304) {          // wtm1p [6][64][128]
        int u = t - 49152;
        int i = u / 8192, r = u % 8192, n = r / 128, cp = r % 128;
        int col = ((cp & 7) << 4) | (cp >> 3);
        wtm1p[u] = f2bf(Wm1[(i * 128 + col) * 64 + n]);
    } else if (t < 196608) {         // wtu0 [6][128][128]
        int u = t - 98304;
        int i = u / 16384, r = u % 16384, n = r / 128, k = r % 128;
        wtu0[u] = f2bf(Wu0[(i * 128 + k) * 128 + n]);
    } else if (t < 245760) {         // wtu1 [6][64][128]
        int u = t - 196608;
        int i = u / 8192, r = u % 8192, n = r / 128, k = r % 128;
        wtu1[u] = f2bf(Wu1[(i * 128 + k) * 64 + n]);
    } else if (t < 246528) {         // wdp [6][128] perm
        int u = t - 245760;
        int i = u / 128, cp = u % 128;
        int col = ((cp & 7) << 4) | (cp >> 3);
        wdp[u] = Wm0[(i * 65 + 64) * 128 + col];
    } else if (t < 247296) {         // bm0p [6][128] perm
        int u = t - 246528;
        int i = u / 128, cp = u % 128;
        int col = ((cp & 7) << 4) | (cp >> 3);
        bm0p[u] = bm0[i * 128 + col];
    } else if (t < 255488) {         // wte0 [256][32]
        int u = t - 247296;
        int n = u / 32, k = u % 32;
        wte0[u] = (k < 11) ? f2bf(eW0[k * 256 + n]) : 0;
    } else if (t < 288256) {         // wte1 [128][256]
        int u = t - 255488;
        int n = u / 256, k = u % 256;
        wte1[u] = f2bf(eW1[k * 128 + n]);
    } else if (t < 296448) {         // wte2 [64][128]
        int u = t - 288256;
        int n = u / 128, k = u % 128;
        wte2[u] = f2bf(eW2[k * 64 + n]);
    } else if (t < 312832) {         // wth0 [256][64]
        int u = t - 296448;
        int n = u / 64, k = u % 64;
        wth0[u] = f2bf(hW0[k * 256 + n]);
    } else if (t < 329216) {         // wth1 [64][256]
        int u = t - 312832;
        int n = u / 256, k = u % 256;
        wth1[u] = f2bf(hW1[k * 64 + n]);
    } else if (t < 329216 + BB * NC) {  // s4 pack with baked validity mask
        int u = t - 329216;
        int b = u / NC, j = u % NC;
        bool ok = j < valid_lens[b];
        float x = ok ? sctx[u * 3] : 1.0e6f;
        float y = ok ? sctx[u * 3 + 1] : 1.0e6f;
        float z = ok ? sctx[u * 3 + 2] : 1.0e6f;
        s4[u] = make_float4(x, y, z, 0.0f);
    }
}

// ---------------- fused top-K (+wave-0 embed/P0 tail): 16 receivers/nodes per block ----------------
__global__ __launch_bounds__(256) void k_topk(
    const float4* __restrict__ s4, const float* __restrict__ s_ctx,
    const float* __restrict__ s_test, const float* __restrict__ f_ctx,
    const float* __restrict__ emb_obs,
    const unsigned short* __restrict__ WT0, const float* __restrict__ b0,
    const unsigned short* __restrict__ WT1, const float* __restrict__ b1,
    const unsigned short* __restrict__ WT2, const float* __restrict__ b2,
    const float* __restrict__ g, const float* __restrict__ bta,
    const unsigned short* __restrict__ Wm0n,     // [128][64] (block 0)
    unsigned short* __restrict__ nodes,
    unsigned short* __restrict__ Pout,           // bf16 [NODES][128] perm
    float* __restrict__ dists, int* __restrict__ senders, float* __restrict__ wout)
{
    __shared__ float cd[4 * 64 * 11];
    __shared__ float slotv[4][4][16];
    __shared__ int   sloti[4][4][16];
    __shared__ int   cnt[4][4];
    __shared__ unsigned short h0s[16 * 256];     // wave-0 embed buffers
    __shared__ unsigned short h1s[16 * 128];
    __shared__ unsigned short xos[16 * 64];
    int wave = threadIdx.x >> 6;
    int lane = threadIdx.x & 63;
    int r0 = blockIdx.x * 16 + wave * 4;
    int b = r0 / NN;
    const float4* sc = s4 + (size_t)b * NC;
    float px[4], py[4], pz[4];
#pragma unroll
    for (int q = 0; q < 4; ++q) {
        int n = (r0 + q) % NN;
        const float* p = (n < NC) ? &s_ctx[(size_t)(b * NC + n) * 3]
                                  : &s_test[(size_t)(b * NT + (n - NC)) * 3];
        px[q] = p[0]; py[q] = p[1]; pz[q] = p[2];
    }
    float bq[4][LM];
#pragma unroll
    for (int q = 0; q < 4; ++q)
#pragma unroll
        for (int k = 0; k < LM; ++k) bq[q][k] = BIGF;
    // passA: per-lane sorted top-5 (union covers wave top-10 w.h.p.)
#pragma unroll 8
    for (int i = 0; i < 64; ++i) {
        int j = lane + (i << 6);
        float4 s = sc[j];
#pragma unroll
        for (int q = 0; q < 4; ++q) {
            float dx = px[q] - s.x, dy = py[q] - s.y, dz = pz[q] - s.z;
            float d2 = fmaf(dx, dx, fmaf(dy, dy, dz * dz));
#pragma unroll
            for (int k = LM - 1; k >= 1; --k)
                bq[q][k] = __builtin_amdgcn_fmed3f(bq[q][k - 1], bq[q][k], d2);
            bq[q][0] = fminf(bq[q][0], d2);
        }
    }
    // merge: T = 10th smallest of the per-lane-top-5 union (wave-uniform)
    int base = (wave * 64 + lane) * 11;
    float T[4];
#pragma unroll
    for (int q = 0; q < 4; ++q) {
#pragma unroll
        for (int k = 0; k < LM; ++k) cd[base + k] = bq[q][k];
        cd[base + LM] = BIGF;
        __builtin_amdgcn_wave_barrier();
        int head = 0;
        float Tl = BIGF;
#pragma unroll
        for (int rr = 0; rr < KNN; ++rr) {
            float v = cd[base + head];
            float mv = v;
#pragma unroll
            for (int off = 32; off > 0; off >>= 1) mv = fminf(mv, __shfl_xor(mv, off, 64));
            unsigned long long ball = __ballot(v == mv);
            int win = __ffsll(ball) - 1;
            if (lane == win) head++;
            Tl = mv;
        }
        T[q] = Tl;
    }
    // passB: collect (v, idx) with v <= T via LDS atomic
    if (lane < 4) cnt[wave][lane] = 0;
    __builtin_amdgcn_wave_barrier();
#pragma unroll 4
    for (int i = 0; i < 64; ++i) {
        int j = lane + (i << 6);
        float4 s = sc[j];
#pragma unroll
        for (int q = 0; q < 4; ++q) {
            float dx = px[q] - s.x, dy = py[q] - s.y, dz = pz[q] - s.z;
            float v = fmaf(dx, dx, fmaf(dy, dy, dz * dz));
            if (v <= T[q]) {
                int slot = atomicAdd(&cnt[wave][q], 1);
                if (slot < 16) { slotv[wave][q][slot] = v; sloti[wave][q][slot] = j; }
            }
        }
    }
    __builtin_amdgcn_wave_barrier();
    // epilogue: rank by (value, index); keep rank<10
#pragma unroll
    for (int q = 0; q < 4; ++q) {
        int count = cnt[wave][q];
        if (count > 16) count = 16;
        float e = 0.0f, d = 0.0f;
        int isel = 0, rank = 0;
        bool own = lane < count;
        if (own) {
            float myv = slotv[wave][q][lane];
            int myi = sloti[wave][q][lane];
            for (int j = 0; j < count; ++j) {
                float vj = slotv[wave][q][j];
                int ij = sloti[wave][q][j];
                rank += (vj < myv || (vj == myv && ij < myi)) ? 1 : 0;
            }
            own = rank < KNN;
            if (own) {
                isel = myi;
                d = sqrtf(myv);
                e = __expf(-d);
            }
        }
        float ssum = wave_sum(e);
        if (own) {
            size_t o = (size_t)(r0 + q) * KNN + rank;
            dists[o] = d;
            senders[o] = isel;
            wout[o] = e / ssum;
        }
    }
    if (wave != 0) return;

    // ================= wave-0 tail: embed 16 nodes (+P0) =================
    {
        int lr = lane & 15, lk = lane >> 4;
        int n0 = blockIdx.x * 16;
        int bq2 = n0 / NN, nloc0 = n0 % NN;
        bool is_ctx = nloc0 < NC;
        int nr = nloc0 + lr;
        float xv[8];
#pragma unroll
        for (int j = 0; j < 8; ++j) xv[j] = 0.0f;
        if (lk == 0) {
            const float* eb = emb_obs + (is_ctx ? 4 : 0);
            xv[0] = eb[0]; xv[1] = eb[1]; xv[2] = eb[2]; xv[3] = eb[3];
            if (is_ctx) {
                const float* sp = s_ctx + ((size_t)(bq2 * NC + nr)) * 3;
                const float* fp = f_ctx + ((size_t)(bq2 * NC + nr)) * 4;
                xv[4] = sp[0]; xv[5] = sp[1]; xv[6] = sp[2]; xv[7] = fp[0];
            } else {
                const float* sp = s_test + ((size_t)(bq2 * NT + nr - NC)) * 3;
                xv[4] = sp[0]; xv[5] = sp[1]; xv[6] = sp[2];
            }
        } else if (lk == 1 && is_ctx) {
            const float* fp = f_ctx + ((size_t)(bq2 * NC + nr)) * 4;
            xv[0] = fp[1]; xv[1] = fp[2]; xv[2] = fp[3];
        }
        short8 a;
#pragma unroll
        for (int j = 0; j < 8; ++j) a[j] = (short)f2bf(xv[j]);

        // GEMM1: [16x32]@[32x256] in 4 groups of 4 (VGPR cap)
#pragma unroll
        for (int gq = 0; gq < 4; ++gq) {
            f32x4 acc0[4];
#pragma unroll
            for (int n4 = 0; n4 < 4; ++n4) {
                int nt = gq * 4 + n4;
                short8 bb = *(const short8*)(WT0 + (nt * 16 + lr) * 32 + lk * 8);
                f32x4 z = (f32x4){0.f, 0.f, 0.f, 0.f};
                acc0[n4] = mfma_bf16(a, bb, z);
            }
#pragma unroll
            for (int n4 = 0; n4 < 4; ++n4) {
                int col = (gq * 4 + n4) * 16 + lr;
                float bias = b0[col];
                int u = col >> 3;
#pragma unroll
                for (int j = 0; j < 4; ++j) {
                    int row = lk * 4 + j;
                    float v = gelu_f(acc0[n4][j] + bias);
                    int us = (u & 16) | ((u ^ row) & 15);
                    h0s[row * 256 + us * 8 + (col & 7)] = f2bf(v);
                }
            }
        }
        // GEMM2: [16x256]@[256x128] in 2 halves of 4
#pragma unroll
        for (int half = 0; half < 2; ++half) {
            f32x4 acc1[4];
#pragma unroll
            for (int n4 = 0; n4 < 4; ++n4) acc1[n4] = (f32x4){0.f, 0.f, 0.f, 0.f};
#pragma unroll
            for (int ks = 0; ks < 8; ++ks) {
                int u = ks * 4 + lk;
                int us = (u & 16) | ((u ^ lr) & 15);
                short8 aa = *(const short8*)(&h0s[lr * 256 + us * 8]);
#pragma unroll
                for (int n4 = 0; n4 < 4; ++n4) {
                    int nt = half * 4 + n4;
                    short8 bb = *(const short8*)(WT1 + (nt * 16 + lr) * 256 + ks * 32 + lk * 8);
                    acc1[n4] = mfma_bf16(aa, bb, acc1[n4]);
                }
            }
#pragma unroll
            for (int n4 = 0; n4 < 4; ++n4) {
                int col = (half * 4 + n4) * 16 + lr;
                float bias = b1[col];
                int u = col >> 3;
#pragma unroll
                for (int j = 0; j < 4; ++j) {
                    int row = lk * 4 + j;
                    float v = gelu_f(acc1[n4][j] + bias);
                    int us = (u ^ row) & 15;
                    h1s[row * 128 + us * 8 + (col & 7)] = f2bf(v);
                }
            }
        }
        // GEMM3: [16x128]@[128x64] + LN
        f32x4 acc2[4];
#pragma unroll
        for (int nt = 0; nt < 4; ++nt) acc2[nt] = (f32x4){0.f, 0.f, 0.f, 0.f};
#pragma unroll
        for (int ks = 0; ks < 4; ++ks) {
            int u = ks * 4 + lk;
            int us = (u ^ lr) & 15;
            short8 aa = *(const short8*)(&h1s[lr * 128 + us * 8]);
#pragma unroll
            for (int nt = 0; nt < 4; ++nt) {
                short8 bb = *(const short8*)(WT2 + (nt * 16 + lr) * 128 + ks * 32 + lk * 8);
                acc2[nt] = mfma_bf16(aa, bb, acc2[nt]);
            }
        }
        float vals[4][4];
#pragma unroll
        for (int j = 0; j < 4; ++j)
#pragma unroll
            for (int nt = 0; nt < 4; ++nt)
                vals[j][nt] = acc2[nt][j] + b2[nt * 16 + lr];
#pragma unroll
        for (int j = 0; j < 4; ++j) {
            int row = lk * 4 + j;
            float s = vals[j][0] + vals[j][1] + vals[j][2] + vals[j][3];
#pragma unroll
            for (int m = 1; m < 16; m <<= 1) s += __shfl_xor(s, m, 64);
            float mean = s * (1.0f / 64.0f);
            float vs = 0.0f;
#pragma unroll
            for (int nt = 0; nt < 4; ++nt) { float dd = vals[j][nt] - mean; vs += dd * dd; }
#pragma unroll
            for (int m = 1; m < 16; m <<= 1) vs += __shfl_xor(vs, m, 64);
            float inv = rsqrtf(vs * (1.0f / 64.0f) + 1e-6f);
            int node = n0 + row;
#pragma unroll
            for (int nt = 0; nt < 4; ++nt) {
                int col = nt * 16 + lr;
                float o = (vals[j][nt] - mean) * inv * g[col] + bta[col];
                unsigned short ob = f2bf(o);
                nodes[(size_t)node * 64 + col] = ob;
                xos[row * 64 + ((col >> 3) ^ (row & 7)) * 8 + (col & 7)] = ob;
            }
        }
        // P0 = ln_out @ Wm0[0][0:64], in 2 halves of 4
#pragma unroll
        for (int half = 0; half < 2; ++half) {
            f32x4 accP[4];
#pragma unroll
            for (int n4 = 0; n4 < 4; ++n4) accP[n4] = (f32x4){0.f, 0.f, 0.f, 0.f};
#pragma unroll
            for (int ks = 0; ks < 2; ++ks) {
                short8 aa = *(const short8*)(&xos[lr * 64 + ((ks * 4 + lk) ^ (lr & 7)) * 8]);
#pragma unroll
                for (int n4 = 0; n4 < 4; ++n4) {
                    int nt = half * 4 + n4;
                    short8 bb = *(const short8*)(Wm0n + (nt * 16 + lr) * 64 + ks * 32 + lk * 8);
                    accP[n4] = mfma_bf16(aa, bb, accP[n4]);
                }
            }
#pragma unroll
            for (int j = 0; j < 4; ++j) {
                int node = n0 + lk * 4 + j;
                uint2 pk2;
                pk2.x = (unsigned int)f2bf(accP[0][j]) | ((unsigned int)f2bf(accP[1][j]) << 16);
                pk2.y = (unsigned int)f2bf(accP[2][j]) | ((unsigned int)f2bf(accP[3][j]) << 16);
                *(uint2*)(Pout + (size_t)node * 128 + lr * 8 + half * 4) = pk2;
            }
        }
    }
}

// ---------------- fused block: 4-wave gather + wave-0 tail (+head on last) ----------------
// 16 nodes per 256-thread block; XCD-swizzled tiles; last iteration: test tiles only
__global__ __launch_bounds__(256) void k_blk(
    const unsigned short* __restrict__ nodes_in,
    const unsigned short* __restrict__ P,        // bf16 [NODES][128] perm (read)
    const float* __restrict__ dists, const int* __restrict__ senders,
    const float* __restrict__ w,
    const float* __restrict__ wdp, const float* __restrict__ bm0p,
    const unsigned short* __restrict__ Wm1p,     // [64][128] (perm k)
    const float* __restrict__ bm1,
    const unsigned short* __restrict__ WTu0,     // [128][128]
    const float* __restrict__ bu0,
    const unsigned short* __restrict__ WTu1,     // [64][128]
    const float* __restrict__ bu1,
    const float* __restrict__ lng, const float* __restrict__ lnb,
    const unsigned short* __restrict__ Wm0n,     // [128][64] next-iter
    const int doP,
    unsigned short* __restrict__ nodes_out,
    unsigned short* __restrict__ Pout,           // ping-pong buffer
    const int doHead, const int testOnly,
    const unsigned short* __restrict__ wth0,     // [256][64]
    const float* __restrict__ hb0,
    const unsigned short* __restrict__ wth1,     // [64][256]
    const float* __restrict__ hb1,
    const float* __restrict__ hW2, const float* __restrict__ hb2,
    float* __restrict__ out)
{
    __shared__ unsigned short X[16 * 64];
    __shared__ unsigned short G[16 * 128];
    __shared__ unsigned short AG[16 * 64];
    __shared__ unsigned short H[16 * 128];
    __shared__ unsigned short XO[16 * 64];
    __shared__ unsigned short HH[16 * 256];
    __shared__ unsigned short HH1[16 * 72];
    __shared__ int   sidE[160];
    __shared__ float dE[160], wE[160];
    int l = threadIdx.x;
    int wave = l >> 6, lane = l & 63;
    int bid = blockIdx.x;
    int tile = testOnly ? ((bid >> 6) * 320 + 256 + (bid & 63))
                        : ((bid & 7) * 160 + (bid >> 3));
    int n0 = tile * 16;
    int b = n0 / NN;
    size_t bbase = (size_t)b * NN;
    int e0 = n0 * KNN;
    if (l < 160) {
        sidE[l] = senders[e0 + l];
        dE[l]   = dists[e0 + l];
        wE[l]   = w[e0 + l];
    }
    if (l < 128) {
        int row = l >> 3, u = l & 7;
        int4v v = *(const int4v*)(nodes_in + ((size_t)(n0 + row)) * 64 + u * 8);
        *(int4v*)(&X[row * 64 + (u ^ (row & 7)) * 8]) = v;
    }
    __syncthreads();
    float wd0 = wdp[2 * lane], wd1 = wdp[2 * lane + 1];
    float bb0 = bm0p[2 * lane], bb1 = bm0p[2 * lane + 1];
    const unsigned int* Pb = (const unsigned int*)P;
    unsigned int* G32 = (unsigned int*)G;
#pragma unroll
    for (int nn = 0; nn < 4; ++nn) {
        int n = wave * 4 + nn;
        float a0 = 0.0f, a1 = 0.0f;
#pragma unroll
        for (int k = 0; k < KNN; ++k) {
            int e = n * KNN + k;
            int sid = sidE[e];
            float dd = dE[e], ww = wE[e];
            unsigned int pr = Pb[(bbase + sid) * 64 + lane];
            float p0 = __uint_as_float(pr << 16);
            float p1 = __uint_as_float(pr & 0xFFFF0000u);
            float g0 = gelu_f(fmaf(dd, wd0, p0 + bb0));
            float g1 = gelu_f(fmaf(dd, wd1, p1 + bb1));
            a0 = fmaf(ww, g0, a0);
            a1 = fmaf(ww, g1, a1);
        }
        unsigned int pk = (unsigned int)f2bf(a0) | ((unsigned int)f2bf(a1) << 16);
        G32[n * 64 + ((lane >> 2) ^ n) * 4 + (lane & 3)] = pk;
    }
    __syncthreads();
    if (wave != 0) return;
    int lr = lane & 15, lk = lane >> 4;
    f32x4 accA[4];
#pragma unroll
    for (int nt = 0; nt < 4; ++nt) accA[nt] = (f32x4){0.f, 0.f, 0.f, 0.f};
#pragma unroll
    for (int ks = 0; ks < 4; ++ks) {
        short8 a = *(const short8*)(&G[lr * 128 + ((ks * 4 + lk) ^ lr) * 8]);
#pragma unroll
        for (int nt = 0; nt < 4; ++nt) {
            short8 bb = *(const short8*)(Wm1p + (nt * 16 + lr) * 128 + ks * 32 + lk * 8);
            accA[nt] = mfma_bf16(a, bb, accA[nt]);
        }
    }
#pragma unroll
    for (int nt = 0; nt < 4; ++nt) {
        int col = nt * 16 + lr;
        float bias = bm1[col];
#pragma unroll
        for (int j = 0; j < 4; ++j) {
            int row = lk * 4 + j;
            AG[row * 64 + ((col >> 3) ^ (row & 7)) * 8 + (col & 7)] =
                f2bf(accA[nt][j] + bias);
        }
    }
    f32x4 acc[8];
#pragma unroll
    for (int nt = 0; nt < 8; ++nt) acc[nt] = (f32x4){0.f, 0.f, 0.f, 0.f};
#pragma unroll
    for (int ks = 0; ks < 4; ++ks) {
        short8 a;
        if (ks < 2) a = *(const short8*)(&X[lr * 64 + ((ks * 4 + lk) ^ (lr & 7)) * 8]);
        else        a = *(const short8*)(&AG[lr * 64 + (((ks - 2) * 4 + lk) ^ (lr & 7)) * 8]);
#pragma unroll
        for (int nt = 0; nt < 8; ++nt) {
            short8 bb = *(const short8*)(WTu0 + (nt * 16 + lr) * 128 + ks * 32 + lk * 8);
            acc[nt] = mfma_bf16(a, bb, acc[nt]);
        }
    }
#pragma unroll
    for (int nt = 0; nt < 8; ++nt) {
        int col = nt * 16 + lr;
        float bias = bu0[col];
#pragma unroll
        for (int j = 0; j < 4; ++j) {
            int lrow = lk * 4 + j;
            float v = gelu_f(acc[nt][j] + bias);
            H[lrow * 128 + ((col >> 3) ^ lrow) * 8 + (col & 7)] = f2bf(v);
        }
    }
    f32x4 acc2[4];
#pragma unroll
    for (int nt = 0; nt < 4; ++nt) acc2[nt] = (f32x4){0.f, 0.f, 0.f, 0.f};
#pragma unroll
    for (int ks = 0; ks < 4; ++ks) {
        short8 a = *(const short8*)(&H[lr * 128 + ((ks * 4 + lk) ^ lr) * 8]);
#pragma unroll
        for (int nt = 0; nt < 4; ++nt) {
            short8 bb = *(const short8*)(WTu1 + (nt * 16 + lr) * 128 + ks * 32 + lk * 8);
            acc2[nt] = mfma_bf16(a, bb, acc2[nt]);
        }
    }
    float vals[4][4];
#pragma unroll
    for (int j = 0; j < 4; ++j) {
        int row = lk * 4 + j;
#pragma unroll
        for (int nt = 0; nt < 4; ++nt) {
            int col = nt * 16 + lr;
            float x = bf2f(X[row * 64 + ((col >> 3) ^ (row & 7)) * 8 + (col & 7)]);
            vals[j][nt] = x + acc2[nt][j] + bu1[col];
        }
    }
#pragma unroll
    for (int j = 0; j < 4; ++j) {
        int row = lk * 4 + j;
        float s = vals[j][0] + vals[j][1] + vals[j][2] + vals[j][3];
#pragma unroll
        for (int mm = 1; mm < 16; mm <<= 1) s += __shfl_xor(s, mm, 64);
        float mean = s * (1.0f / 64.0f);
        float vs = 0.0f;
#pragma unroll
        for (int nt = 0; nt < 4; ++nt) { float d = vals[j][nt] - mean; vs += d * d; }
#pragma unroll
        for (int mm = 1; mm < 16; mm <<= 1) vs += __shfl_xor(vs, mm, 64);
        float inv = rsqrtf(vs * (1.0f / 64.0f) + 1e-6f);
#pragma unroll
        for (int nt = 0; nt < 4; ++nt) {
            int col = nt * 16 + lr;
            float o = (vals[j][nt] - mean) * inv * lng[col] + lnb[col];
            unsigned short ob = f2bf(o);
            nodes_out[((size_t)(n0 + row)) * 64 + col] = ob;
            XO[row * 64 + ((col >> 3) ^ (row & 7)) * 8 + (col & 7)] = ob;
        }
    }
    if (doP) {
        f32x4 accP[8];
#pragma unroll
        for (int nt = 0; nt < 8; ++nt) accP[nt] = (f32x4){0.f, 0.f, 0.f, 0.f};
#pragma unroll
        for (int ks = 0; ks < 2; ++ks) {
            short8 aa = *(const short8*)(&XO[lr * 64 + ((ks * 4 + lk) ^ (lr & 7)) * 8]);
#pragma unroll
            for (int nt = 0; nt < 8; ++nt) {
                short8 bb = *(const short8*)(Wm0n + (nt * 16 + lr) * 64 + ks * 32 + lk * 8);
                accP[nt] = mfma_bf16(aa, bb, accP[nt]);
            }
        }
#pragma unroll
        for (int j = 0; j < 4; ++j) {
            int node = n0 + lk * 4 + j;
            short8 ps;
#pragma unroll
            for (int nt = 0; nt < 8; ++nt) ps[nt] = (short)f2bf(accP[nt][j]);
            *(short8*)(Pout + (size_t)node * 128 + lr * 8) = ps;
        }
    }
    if (doHead) {
        int nloc = n0 % NN;
        int bq = n0 / NN;
#pragma unroll
        for (int half = 0; half < 2; ++half) {
            f32x4 ah[8];
#pragma unroll
            for (int nt = 0; nt < 8; ++nt) ah[nt] = (f32x4){0.f, 0.f, 0.f, 0.f};
#pragma unroll
            for (int ks = 0; ks < 2; ++ks) {
                short8 aa = *(const short8*)(&XO[lr * 64 + ((ks * 4 + lk) ^ (lr & 7)) * 8]);
#pragma unroll
                for (int nt = 0; nt < 8; ++nt) {
                    int col16 = half * 8 + nt;
                    short8 bb = *(const short8*)(wth0 + (col16 * 16 + lr) * 64 + ks * 32 + lk * 8);
                    ah[nt] = mfma_bf16(aa, bb, ah[nt]);
                }
            }
#pragma unroll
            for (int nt = 0; nt < 8; ++nt) {
                int col = (half * 8 + nt) * 16 + lr;
                float bias = hb0[col];
                int u = col >> 3;
#pragma unroll
                for (int j = 0; j < 4; ++j) {
                    int row = lk * 4 + j;
                    float v = gelu_f(ah[nt][j] + bias);
                    int us = (u & 16) | ((u ^ row) & 15);
                    HH[row * 256 + us * 8 + (col & 7)] = f2bf(v);
                }
            }
        }
        f32x4 a1h[4];
#pragma unroll
        for (int nt = 0; nt < 4; ++nt) a1h[nt] = (f32x4){0.f, 0.f, 0.f, 0.f};
#pragma unroll
        for (int ks = 0; ks < 8; ++ks) {
            int u = ks * 4 + lk;
            int us = (u & 16) | ((u ^ lr) & 15);
            short8 aa = *(const short8*)(&HH[lr * 256 + us * 8]);
#pragma unroll
            for (int nt = 0; nt < 4; ++nt) {
                short8 bb = *(const short8*)(wth1 + (nt * 16 + lr) * 256 + ks * 32 + lk * 8);
                a1h[nt] = mfma_bf16(aa, bb, a1h[nt]);
            }
        }
#pragma unroll
        for (int nt = 0; nt < 4; ++nt) {
            int col = nt * 16 + lr;
            float bias = hb1[col];
#pragma unroll
            for (int j = 0; j < 4; ++j) {
                int row = lk * 4 + j;
                HH1[row * 72 + col] = f2bf(gelu_f(a1h[nt][j] + bias));
            }
        }
        int task = lane >> 1;
        int row = task >> 1;
        int o = task & 1;
        int t2 = lane & 1;
        float pp = 0.0f;
#pragma unroll
        for (int d = 0; d < 32; ++d) {
            int dd = t2 * 32 + d;
            pp += bf2f(HH1[row * 72 + dd]) * hW2[dd * 2 + o];
        }
        pp += __shfl_xor(pp, 1, 64);
        if (t2 == 0) {
            int gg = bq * NT + (nloc - NC) + row;
            if (o == 0) out[gg] = pp + hb2[0];
            else        out[BB * NT + gg] = __expf(0.5f * (pp + hb2[1]));
        }
    }
}

extern "C" void kernel_launch(void* const* d_in, const int* in_sizes, int n_in,
                              void* d_out, int out_size, void* d_ws, size_t ws_size,
                              hipStream_t stream)
{
    (void)in_sizes; (void)n_in; (void)out_size; (void)ws_size;
    const float* s_ctx   = (const float*)d_in[0];
    const float* f_ctx   = (const float*)d_in[1];
    const float* s_test  = (const float*)d_in[2];
    const int*   valid   = (const int*)d_in[3];
    const float* emb_obs = (const float*)d_in[4];
    const float* ea_W0   = (const float*)d_in[5];
    const float* ea_b0   = (const float*)d_in[6];
    const float* ea_W1   = (const float*)d_in[7];
    const float* ea_b1   = (const float*)d_in[8];
    const float* ea_W2   = (const float*)d_in[9];
    const float* ea_b2   = (const float*)d_in[10];
    const float* ln_g    = (const float*)d_in[11];
    const float* ln_b    = (const float*)d_in[12];
    const float* blk_Wm0 = (const float*)d_in[13];
    const float* blk_bm0 = (const float*)d_in[14];
    const float* blk_Wm1 = (const float*)d_in[15];
    const float* blk_bm1 = (const float*)d_in[16];
    const float* blk_Wu0 = (const float*)d_in[17];
    const float* blk_bu0 = (const float*)d_in[18];
    const float* blk_Wu1 = (const float*)d_in[19];
    const float* blk_bu1 = (const float*)d_in[20];
    const float* blk_lng = (const float*)d_in[21];
    const float* blk_lnb = (const float*)d_in[22];
    const float* hd_W0   = (const float*)d_in[23];
    const float* hd_b0   = (const float*)d_in[24];
    const float* hd_W1   = (const float*)d_in[25];
    const float* hd_b1   = (const float*)d_in[26];
    const float* hd_W2   = (const float*)d_in[27];
    const float* hd_b2   = (const float*)d_in[28];

    char* p = (char*)d_ws;
    auto alloc = [&](size_t bytes) { char* r = p; p += (bytes + 255) & ~(size_t)255; return r; };
    unsigned short* nodesA = (unsigned short*)alloc((size_t)NODES * 64 * 2);
    unsigned short* nodesB = (unsigned short*)alloc((size_t)NODES * 64 * 2);
    unsigned short* PA     = (unsigned short*)alloc((size_t)NODES * 128 * 2);
    unsigned short* PB     = (unsigned short*)alloc((size_t)NODES * 128 * 2);
    float* dists   = (float*)alloc((size_t)NODES * KNN * 4);
    float* wbuf    = (float*)alloc((size_t)NODES * KNN * 4);
    int*   senders = (int*)alloc((size_t)NODES * KNN * 4);
    unsigned short* wtm0  = (unsigned short*)alloc((size_t)6 * 8192 * 2);
    unsigned short* wtm1p = (unsigned short*)alloc((size_t)6 * 8192 * 2);
    unsigned short* wtu0  = (unsigned short*)alloc((size_t)6 * 16384 * 2);
    unsigned short* wtu1  = (unsigned short*)alloc((size_t)6 * 8192 * 2);
    float* wdp  = (float*)alloc((size_t)6 * 128 * 4);
    float* bm0p = (float*)alloc((size_t)6 * 128 * 4);
    unsigned short* wte0 = (unsigned short*)alloc((size_t)8192 * 2);
    unsigned short* wte1 = (unsigned short*)alloc((size_t)32768 * 2);
    unsigned short* wte2 = (unsigned short*)alloc((size_t)8192 * 2);
    unsigned short* wth0 = (unsigned short*)alloc((size_t)16384 * 2);
    unsigned short* wth1 = (unsigned short*)alloc((size_t)16384 * 2);
    float4* s4 = (float4*)alloc((size_t)BB * NC * 16);

    k_convw<<<1350, 256, 0, stream>>>(
        blk_Wm0, blk_Wm1, blk_Wu0, blk_Wu1, blk_bm0,
        ea_W0, ea_W1, ea_W2, hd_W0, hd_W1, s_ctx, valid,
        wtm0, wtm1p, wtu0, wtu1, wdp, bm0p, wte0, wte1, wte2, wth0, wth1, s4);

    k_topk<<<NODES / 16, 256, 0, stream>>>(s4, s_ctx, s_test, f_ctx, emb_obs,
        wte0, ea_b0, wte1, ea_b1, wte2, ea_b2, ln_g, ln_b, wtm0,
        nodesA, PA, dists, senders, wbuf);

    unsigned short* nin = nodesA; unsigned short* nout = nodesB;
    unsigned short* pin = PA;     unsigned short* pout = PB;
    for (int i = 0; i < NBLK; ++i) {
        int doP = (i < NBLK - 1) ? 1 : 0;
        int doHead = (i == NBLK - 1) ? 1 : 0;
        int testOnly = doHead;
        int grid = testOnly ? (BB * NT / 16) : (NODES / 16);
        const unsigned short* wm0n = wtm0 + (size_t)((i + 1) % NBLK) * 8192;
        k_blk<<<grid, 256, 0, stream>>>(nin, pin, dists, senders, wbuf,
            wdp + (size_t)i * 128, bm0p + (size_t)i * 128,
            wtm1p + (size_t)i * 8192, blk_bm1 + (size_t)i * 64,
            wtu0 + (size_t)i * 16384, blk_bu0 + (size_t)i * 128,
            wtu1 + (size_t)i * 8192, blk_bu1 + (size_t)i * 64,
            blk_lng + (size_t)i * 64, blk_lnb + (size_t)i * 64,
            wm0n, doP, nout, pout,
            doHead, testOnly, wth0, hd_b0, wth1, hd_b1, hd_W2, hd_b2, (float*)d_out);
        unsigned short* tmp = nin; nin = nout; nout = tmp;
        tmp = pin; pin = pout; pout = tmp;
    }
}

// Round 15
// 267.510 us; speedup vs baseline: 1.1518x; 1.1518x over previous
//
#include <hip/hip_runtime.h>
#include <math.h>

#define BB 4
#define NC 4096
#define NT 1024
#define NN (NC + NT)      // 5120
#define NODES (BB * NN)   // 20480
#define DD 64
#define KNN 10
#define NBLK 6
#define BIGF 3.0e38f
#define LM 5              // per-lane kept candidates (union covers global top-10, p_fail ~ 2e-7)

typedef __attribute__((ext_vector_type(8))) short short8;
typedef __attribute__((ext_vector_type(4))) float f32x4;
typedef __attribute__((ext_vector_type(4))) int int4v;

__device__ __forceinline__ unsigned short f2bf(float f) {
    unsigned int u = __float_as_uint(f);
    unsigned int r = (u + 0x7fffu + ((u >> 16) & 1u)) >> 16;
    return (unsigned short)r;
}
__device__ __forceinline__ float bf2f(unsigned short h) {
    return __uint_as_float(((unsigned int)h) << 16);
}

__device__ __forceinline__ float gelu_f(float x) {
    const float c0 = 0.7978845608028654f;
    float x3 = x * x * x;
    float z2 = 2.0f * c0 * (x + 0.044715f * x3);
    float e = __expf(z2);
    float r = __builtin_amdgcn_rcpf(1.0f + e);
    return x - x * r;
}

__device__ __forceinline__ float wave_sum(float v) {
#pragma unroll
    for (int off = 32; off > 0; off >>= 1) v += __shfl_xor(v, off, 64);
    return v;
}

__device__ __forceinline__ f32x4 mfma_bf16(short8 a, short8 b, f32x4 c) {
    asm("v_mfma_f32_16x16x32_bf16 %0, %1, %2, %0" : "+v"(c) : "v"(a), "v"(b));
    return c;
}

// perm(col) = (col&15)*8 + (col>>4); invperm(cp) = ((cp&7)<<4) | (cp>>3)

// ---------------- weight convert + masked s4 pack ----------------
__global__ __launch_bounds__(256) void k_convw(
    const float* __restrict__ Wm0, const float* __restrict__ Wm1,
    const float* __restrict__ Wu0, const float* __restrict__ Wu1,
    const float* __restrict__ bm0,
    const float* __restrict__ eW0, const float* __restrict__ eW1,
    const float* __restrict__ eW2,
    const float* __restrict__ hW0, const float* __restrict__ hW1,
    const float* __restrict__ sctx, const int* __restrict__ valid_lens,
    unsigned short* __restrict__ wtm0, unsigned short* __restrict__ wtm1p,
    unsigned short* __restrict__ wtu0, unsigned short* __restrict__ wtu1,
    float* __restrict__ wdp, float* __restrict__ bm0p,
    unsigned short* __restrict__ wte0, unsigned short* __restrict__ wte1,
    unsigned short* __restrict__ wte2,
    unsigned short* __restrict__ wth0, unsigned short* __restrict__ wth1,
    float4* __restrict__ s4)
{
    int t = blockIdx.x * 256 + threadIdx.x;
    if (t < 49152) {                 // wtm0 [6][128][64]
        int i = t / 8192, r = t % 8192, n = r / 64, k = r % 64;
        wtm0[t] = f2bf(Wm0[(i * 65 + k) * 128 + n]);
    } else if (t < 98304) {          // wtm1p [6][64][128]
        int u = t - 49152;
        int i = u / 8192, r = u % 8192, n = r / 128, cp = r % 128;
        int col = ((cp & 7) << 4) | (cp >> 3);
        wtm1p[u] = f2bf(Wm1[(i * 128 + col) * 64 + n]);
    } else if (t < 196608) {         // wtu0 [6][128][128]
        int u = t - 98304;
        int i = u / 16384, r = u % 16384, n = r / 128, k = r % 128;
        wtu0[u] = f2bf(Wu0[(i * 128 + k) * 128 + n]);
    } else if (t < 245760) {         // wtu1 [6][64][128]
        int u = t - 196608;
        int i = u / 8192, r = u % 8192, n = r / 128, k = r % 128;
        wtu1[u] = f2bf(Wu1[(i * 128 + k) * 64 + n]);
    } else if (t < 246528) {         // wdp [6][128] perm
        int u = t - 245760;
        int i = u / 128, cp = u % 128;
        int col = ((cp & 7) << 4) | (cp >> 3);
        wdp[u] = Wm0[(i * 65 + 64) * 128 + col];
    } else if (t < 247296) {         // bm0p [6][128] perm
        int u = t - 246528;
        int i = u / 128, cp = u % 128;
        int col = ((cp & 7) << 4) | (cp >> 3);
        bm0p[u] = bm0[i * 128 + col];
    } else if (t < 255488) {         // wte0 [256][32]
        int u = t - 247296;
        int n = u / 32, k = u % 32;
        wte0[u] = (k < 11) ? f2bf(eW0[k * 256 + n]) : 0;
    } else if (t < 288256) {         // wte1 [128][256]
        int u = t - 255488;
        int n = u / 256, k = u % 256;
        wte1[u] = f2bf(eW1[k * 128 + n]);
    } else if (t < 296448) {         // wte2 [64][128]
        int u = t - 288256;
        int n = u / 128, k = u % 128;
        wte2[u] = f2bf(eW2[k * 64 + n]);
    } else if (t < 312832) {         // wth0 [256][64]
        int u = t - 296448;
        int n = u / 64, k = u % 64;
        wth0[u] = f2bf(hW0[k * 256 + n]);
    } else if (t < 329216) {         // wth1 [64][256]
        int u = t - 312832;
        int n = u / 256, k = u % 256;
        wth1[u] = f2bf(hW1[k * 64 + n]);
    } else if (t < 329216 + BB * NC) {  // s4 pack with baked validity mask
        int u = t - 329216;
        int b = u / NC, j = u % NC;
        bool ok = j < valid_lens[b];
        float x = ok ? sctx[u * 3] : 1.0e6f;
        float y = ok ? sctx[u * 3 + 1] : 1.0e6f;
        float z = ok ? sctx[u * 3 + 2] : 1.0e6f;
        s4[u] = make_float4(x, y, z, 0.0f);
    }
}

// ---------------- embed (MFMA) + P0: 64 nodes per WG, 4 waves, barrier-free ----------------
__global__ __launch_bounds__(256) void k_embed2(
    const float* __restrict__ s_ctx, const float* __restrict__ f_ctx,
    const float* __restrict__ s_test, const float* __restrict__ emb_obs,
    const unsigned short* __restrict__ WT0, const float* __restrict__ b0,
    const unsigned short* __restrict__ WT1, const float* __restrict__ b1,
    const unsigned short* __restrict__ WT2, const float* __restrict__ b2,
    const float* __restrict__ g, const float* __restrict__ bta,
    const unsigned short* __restrict__ Wm0n,     // [128][64] (block 0)
    unsigned short* __restrict__ nodes,
    unsigned short* __restrict__ Pout)           // bf16 [NODES][128] perm
{
    __shared__ unsigned short H0[4][16 * 256];
    __shared__ unsigned short H1[4][16 * 128];
    __shared__ unsigned short XO[4][16 * 64];
    int t = threadIdx.x;
    int wave = t >> 6, lane = t & 63, lr = lane & 15, lk = lane >> 4;
    int rb = wave * 16;
    int n0 = blockIdx.x * 64;
    int bq = n0 / NN, nloc0 = n0 % NN;
    bool is_ctx = nloc0 < NC;
    int nr = nloc0 + rb + lr;
    float xv[8];
#pragma unroll
    for (int j = 0; j < 8; ++j) xv[j] = 0.0f;
    if (lk == 0) {
        const float* eb = emb_obs + (is_ctx ? 4 : 0);
        xv[0] = eb[0]; xv[1] = eb[1]; xv[2] = eb[2]; xv[3] = eb[3];
        if (is_ctx) {
            const float* sp = s_ctx + ((size_t)(bq * NC + nr)) * 3;
            const float* fp = f_ctx + ((size_t)(bq * NC + nr)) * 4;
            xv[4] = sp[0]; xv[5] = sp[1]; xv[6] = sp[2]; xv[7] = fp[0];
        } else {
            const float* sp = s_test + ((size_t)(bq * NT + nr - NC)) * 3;
            xv[4] = sp[0]; xv[5] = sp[1]; xv[6] = sp[2];
        }
    } else if (lk == 1 && is_ctx) {
        const float* fp = f_ctx + ((size_t)(bq * NC + nr)) * 4;
        xv[0] = fp[1]; xv[1] = fp[2]; xv[2] = fp[3];
    }
    short8 a;
#pragma unroll
    for (int j = 0; j < 8; ++j) a[j] = (short)f2bf(xv[j]);

    f32x4 acc0[16];
#pragma unroll
    for (int nt = 0; nt < 16; ++nt) {
        short8 bb = *(const short8*)(WT0 + (nt * 16 + lr) * 32 + lk * 8);
        f32x4 z = (f32x4){0.f, 0.f, 0.f, 0.f};
        acc0[nt] = mfma_bf16(a, bb, z);
    }
    unsigned short* h0 = &H0[wave][0];
#pragma unroll
    for (int nt = 0; nt < 16; ++nt) {
        int col = nt * 16 + lr;
        float bias = b0[col];
        int u = col >> 3;
#pragma unroll
        for (int j = 0; j < 4; ++j) {
            int row = lk * 4 + j;
            float v = gelu_f(acc0[nt][j] + bias);
            int us = (u & 16) | ((u ^ row) & 15);
            h0[row * 256 + us * 8 + (col & 7)] = f2bf(v);
        }
    }
    f32x4 acc1[8];
#pragma unroll
    for (int nt = 0; nt < 8; ++nt) acc1[nt] = (f32x4){0.f, 0.f, 0.f, 0.f};
#pragma unroll
    for (int ks = 0; ks < 8; ++ks) {
        int u = ks * 4 + lk;
        int us = (u & 16) | ((u ^ lr) & 15);
        short8 aa = *(const short8*)(&h0[lr * 256 + us * 8]);
#pragma unroll
        for (int nt = 0; nt < 8; ++nt) {
            short8 bb = *(const short8*)(WT1 + (nt * 16 + lr) * 256 + ks * 32 + lk * 8);
            acc1[nt] = mfma_bf16(aa, bb, acc1[nt]);
        }
    }
    unsigned short* h1 = &H1[wave][0];
#pragma unroll
    for (int nt = 0; nt < 8; ++nt) {
        int col = nt * 16 + lr;
        float bias = b1[col];
        int u = col >> 3;
#pragma unroll
        for (int j = 0; j < 4; ++j) {
            int row = lk * 4 + j;
            float v = gelu_f(acc1[nt][j] + bias);
            int us = (u ^ row) & 15;
            h1[row * 128 + us * 8 + (col & 7)] = f2bf(v);
        }
    }
    f32x4 acc2[4];
#pragma unroll
    for (int nt = 0; nt < 4; ++nt) acc2[nt] = (f32x4){0.f, 0.f, 0.f, 0.f};
#pragma unroll
    for (int ks = 0; ks < 4; ++ks) {
        int u = ks * 4 + lk;
        int us = (u ^ lr) & 15;
        short8 aa = *(const short8*)(&h1[lr * 128 + us * 8]);
#pragma unroll
        for (int nt = 0; nt < 4; ++nt) {
            short8 bb = *(const short8*)(WT2 + (nt * 16 + lr) * 128 + ks * 32 + lk * 8);
            acc2[nt] = mfma_bf16(aa, bb, acc2[nt]);
        }
    }
    float vals[4][4];
#pragma unroll
    for (int j = 0; j < 4; ++j)
#pragma unroll
        for (int nt = 0; nt < 4; ++nt)
            vals[j][nt] = acc2[nt][j] + b2[nt * 16 + lr];
    unsigned short* xo = &XO[wave][0];
#pragma unroll
    for (int j = 0; j < 4; ++j) {
        float s = vals[j][0] + vals[j][1] + vals[j][2] + vals[j][3];
#pragma unroll
        for (int m = 1; m < 16; m <<= 1) s += __shfl_xor(s, m, 64);
        float mean = s * (1.0f / 64.0f);
        float vs = 0.0f;
#pragma unroll
        for (int nt = 0; nt < 4; ++nt) { float d = vals[j][nt] - mean; vs += d * d; }
#pragma unroll
        for (int m = 1; m < 16; m <<= 1) vs += __shfl_xor(vs, m, 64);
        float inv = rsqrtf(vs * (1.0f / 64.0f) + 1e-6f);
        int row = lk * 4 + j;
        int node = n0 + rb + row;
#pragma unroll
        for (int nt = 0; nt < 4; ++nt) {
            int col = nt * 16 + lr;
            float o = (vals[j][nt] - mean) * inv * g[col] + bta[col];
            unsigned short ob = f2bf(o);
            nodes[(size_t)node * 64 + col] = ob;
            xo[row * 64 + ((col >> 3) ^ (row & 7)) * 8 + (col & 7)] = ob;
        }
    }
    // P0 = ln_out @ Wm0[0][0:64]
    f32x4 accP[8];
#pragma unroll
    for (int nt = 0; nt < 8; ++nt) accP[nt] = (f32x4){0.f, 0.f, 0.f, 0.f};
#pragma unroll
    for (int ks = 0; ks < 2; ++ks) {
        short8 aa = *(const short8*)(&xo[lr * 64 + ((ks * 4 + lk) ^ (lr & 7)) * 8]);
#pragma unroll
        for (int nt = 0; nt < 8; ++nt) {
            short8 bb = *(const short8*)(Wm0n + (nt * 16 + lr) * 64 + ks * 32 + lk * 8);
            accP[nt] = mfma_bf16(aa, bb, accP[nt]);
        }
    }
#pragma unroll
    for (int j = 0; j < 4; ++j) {
        int node = n0 + rb + lk * 4 + j;
        short8 ps;
#pragma unroll
        for (int nt = 0; nt < 8; ++nt) ps[nt] = (short)f2bf(accP[nt][j]);
        *(short8*)(Pout + (size_t)node * 128 + lr * 8) = ps;
    }
}

// ---------------- top-K: per-lane top-5 med3 + LDS-atomic collection passB ----------------
__global__ __launch_bounds__(256) void k_topk(
    const float4* __restrict__ s4, const float* __restrict__ s_ctx,
    const float* __restrict__ s_test,
    float* __restrict__ dists, int* __restrict__ senders, float* __restrict__ wout)
{
    __shared__ float cd[4 * 64 * 11];
    __shared__ float slotv[4][4][16];
    __shared__ int   sloti[4][4][16];
    __shared__ int   cnt[4][4];
    int wave = threadIdx.x >> 6;
    int lane = threadIdx.x & 63;
    int r0 = blockIdx.x * 16 + wave * 4;
    int b = r0 / NN;
    const float4* sc = s4 + (size_t)b * NC;
    float px[4], py[4], pz[4];
#pragma unroll
    for (int q = 0; q < 4; ++q) {
        int n = (r0 + q) % NN;
        const float* p = (n < NC) ? &s_ctx[(size_t)(b * NC + n) * 3]
                                  : &s_test[(size_t)(b * NT + (n - NC)) * 3];
        px[q] = p[0]; py[q] = p[1]; pz[q] = p[2];
    }
    float bq[4][LM];
#pragma unroll
    for (int q = 0; q < 4; ++q)
#pragma unroll
        for (int k = 0; k < LM; ++k) bq[q][k] = BIGF;
    // passA: per-lane sorted top-5 (union covers wave top-10 w.h.p.)
#pragma unroll 8
    for (int i = 0; i < 64; ++i) {
        int j = lane + (i << 6);
        float4 s = sc[j];
#pragma unroll
        for (int q = 0; q < 4; ++q) {
            float dx = px[q] - s.x, dy = py[q] - s.y, dz = pz[q] - s.z;
            float d2 = fmaf(dx, dx, fmaf(dy, dy, dz * dz));
#pragma unroll
            for (int k = LM - 1; k >= 1; --k)
                bq[q][k] = __builtin_amdgcn_fmed3f(bq[q][k - 1], bq[q][k], d2);
            bq[q][0] = fminf(bq[q][0], d2);
        }
    }
    // merge: T = 10th smallest of the per-lane-top-5 union (wave-uniform)
    int base = (wave * 64 + lane) * 11;
    float T[4];
#pragma unroll
    for (int q = 0; q < 4; ++q) {
#pragma unroll
        for (int k = 0; k < LM; ++k) cd[base + k] = bq[q][k];
        cd[base + LM] = BIGF;                  // sentinel: lane exhausted
        __builtin_amdgcn_wave_barrier();
        int head = 0;
        float Tl = BIGF;
#pragma unroll
        for (int rr = 0; rr < KNN; ++rr) {
            float v = cd[base + head];
            float mv = v;
#pragma unroll
            for (int off = 32; off > 0; off >>= 1) mv = fminf(mv, __shfl_xor(mv, off, 64));
            unsigned long long ball = __ballot(v == mv);
            int win = __ffsll(ball) - 1;
            if (lane == win) head++;
            Tl = mv;
        }
        T[q] = Tl;
    }
    // passB: collect (v, idx) with v <= T via LDS atomic (rare hits, ~10/receiver)
    if (lane < 4) cnt[wave][lane] = 0;
    __builtin_amdgcn_wave_barrier();
#pragma unroll 4
    for (int i = 0; i < 64; ++i) {
        int j = lane + (i << 6);
        float4 s = sc[j];
#pragma unroll
        for (int q = 0; q < 4; ++q) {
            float dx = px[q] - s.x, dy = py[q] - s.y, dz = pz[q] - s.z;
            float v = fmaf(dx, dx, fmaf(dy, dy, dz * dz));
            if (v <= T[q]) {
                int slot = atomicAdd(&cnt[wave][q], 1);
                if (slot < 16) { slotv[wave][q][slot] = v; sloti[wave][q][slot] = j; }
            }
        }
    }
    __builtin_amdgcn_wave_barrier();
    // epilogue: rank collected items by (value, index); keep rank<10
#pragma unroll
    for (int q = 0; q < 4; ++q) {
        int count = cnt[wave][q];
        if (count > 16) count = 16;
        float e = 0.0f, d = 0.0f;
        int isel = 0, rank = 0;
        bool own = lane < count;
        if (own) {
            float myv = slotv[wave][q][lane];
            int myi = sloti[wave][q][lane];
            for (int j = 0; j < count; ++j) {
                float vj = slotv[wave][q][j];
                int ij = sloti[wave][q][j];
                rank += (vj < myv || (vj == myv && ij < myi)) ? 1 : 0;
            }
            own = rank < KNN;
            if (own) {
                isel = myi;
                d = sqrtf(myv);
                e = __expf(-d);
            }
        }
        float ssum = wave_sum(e);
        if (own) {
            size_t o = (size_t)(r0 + q) * KNN + rank;
            dists[o] = d;
            senders[o] = isel;
            wout[o] = e / ssum;
        }
    }
}

// ---------------- fused block: 4-wave gather + 2-wave split GEMM tail (+head on last) ----------------
// 16 nodes per 256-thread block; XCD-swizzled tiles; last iteration: test tiles only
__global__ __launch_bounds__(256) void k_blk(
    const unsigned short* __restrict__ nodes_in,
    const unsigned short* __restrict__ P,        // bf16 [NODES][128] perm (read)
    const float* __restrict__ dists, const int* __restrict__ senders,
    const float* __restrict__ w,
    const float* __restrict__ wdp, const float* __restrict__ bm0p,
    const unsigned short* __restrict__ Wm1p,     // [64][128] (perm k)
    const float* __restrict__ bm1,
    const unsigned short* __restrict__ WTu0,     // [128][128]
    const float* __restrict__ bu0,
    const unsigned short* __restrict__ WTu1,     // [64][128]
    const float* __restrict__ bu1,
    const float* __restrict__ lng, const float* __restrict__ lnb,
    const unsigned short* __restrict__ Wm0n,     // [128][64] next-iter
    const int doP,
    unsigned short* __restrict__ nodes_out,
    unsigned short* __restrict__ Pout,           // ping-pong buffer
    const int doHead, const int testOnly,
    const unsigned short* __restrict__ wth0,     // [256][64]
    const float* __restrict__ hb0,
    const unsigned short* __restrict__ wth1,     // [64][256]
    const float* __restrict__ hb1,
    const float* __restrict__ hW2, const float* __restrict__ hb2,
    float* __restrict__ out)
{
    __shared__ unsigned short X[16 * 64];
    __shared__ unsigned short G[16 * 128];
    __shared__ unsigned short AG[16 * 64];
    __shared__ unsigned short H[16 * 128];
    __shared__ unsigned short XO[16 * 64];
    __shared__ float VF[16 * 65];                // f32 staging for split LN
    __shared__ unsigned short HH[16 * 256];
    __shared__ unsigned short HH1[16 * 72];
    __shared__ int   sidE[160];
    __shared__ float dE[160], wE[160];
    int l = threadIdx.x;
    int wave = l >> 6, lane = l & 63;
    int bid = blockIdx.x;
    int tile = testOnly ? ((bid >> 6) * 320 + 256 + (bid & 63))
                        : ((bid & 7) * 160 + (bid >> 3));
    int n0 = tile * 16;
    int b = n0 / NN;
    size_t bbase = (size_t)b * NN;
    int e0 = n0 * KNN;
    if (l < 160) {
        sidE[l] = senders[e0 + l];
        dE[l]   = dists[e0 + l];
        wE[l]   = w[e0 + l];
    }
    if (l < 128) {
        int row = l >> 3, u = l & 7;
        int4v v = *(const int4v*)(nodes_in + ((size_t)(n0 + row)) * 64 + u * 8);
        *(int4v*)(&X[row * 64 + (u ^ (row & 7)) * 8]) = v;
    }
    __syncthreads();
    // gather + gelu + weighted sum -> G; wave w handles nodes w*4 .. w*4+3
    float wd0 = wdp[2 * lane], wd1 = wdp[2 * lane + 1];
    float bb0 = bm0p[2 * lane], bb1 = bm0p[2 * lane + 1];
    const unsigned int* Pb = (const unsigned int*)P;
    unsigned int* G32 = (unsigned int*)G;
#pragma unroll
    for (int nn = 0; nn < 4; ++nn) {
        int n = wave * 4 + nn;
        float a0 = 0.0f, a1 = 0.0f;
#pragma unroll
        for (int k = 0; k < KNN; ++k) {
            int e = n * KNN + k;
            int sid = sidE[e];
            float dd = dE[e], ww = wE[e];
            unsigned int pr = Pb[(bbase + sid) * 64 + lane];
            float p0 = __uint_as_float(pr << 16);
            float p1 = __uint_as_float(pr & 0xFFFF0000u);
            float g0 = gelu_f(fmaf(dd, wd0, p0 + bb0));
            float g1 = gelu_f(fmaf(dd, wd1, p1 + bb1));
            a0 = fmaf(ww, g0, a0);
            a1 = fmaf(ww, g1, a1);
        }
        unsigned int pk = (unsigned int)f2bf(a0) | ((unsigned int)f2bf(a1) << 16);
        G32[n * 64 + ((lane >> 2) ^ n) * 4 + (lane & 3)] = pk;
    }
    __syncthreads();
    int lr = lane & 15, lk = lane >> 4;
    // ---- stage 1: GEMM_A split across waves 0,1 (2 nt each) ----
    if (wave < 2) {
        f32x4 accA[2];
#pragma unroll
        for (int n2 = 0; n2 < 2; ++n2) accA[n2] = (f32x4){0.f, 0.f, 0.f, 0.f};
#pragma unroll
        for (int ks = 0; ks < 4; ++ks) {
            short8 a = *(const short8*)(&G[lr * 128 + ((ks * 4 + lk) ^ lr) * 8]);
#pragma unroll
            for (int n2 = 0; n2 < 2; ++n2) {
                int nt = wave * 2 + n2;
                short8 bb = *(const short8*)(Wm1p + (nt * 16 + lr) * 128 + ks * 32 + lk * 8);
                accA[n2] = mfma_bf16(a, bb, accA[n2]);
            }
        }
#pragma unroll
        for (int n2 = 0; n2 < 2; ++n2) {
            int col = (wave * 2 + n2) * 16 + lr;
            float bias = bm1[col];
#pragma unroll
            for (int j = 0; j < 4; ++j) {
                int row = lk * 4 + j;
                AG[row * 64 + ((col >> 3) ^ (row & 7)) * 8 + (col & 7)] =
                    f2bf(accA[n2][j] + bias);
            }
        }
    }
    __syncthreads();
    // ---- stage 2: GEMM3 split across waves 0,1 (4 nt each) ----
    if (wave < 2) {
        f32x4 acc[4];
#pragma unroll
        for (int n4 = 0; n4 < 4; ++n4) acc[n4] = (f32x4){0.f, 0.f, 0.f, 0.f};
#pragma unroll
        for (int ks = 0; ks < 4; ++ks) {
            short8 a;
            if (ks < 2) a = *(const short8*)(&X[lr * 64 + ((ks * 4 + lk) ^ (lr & 7)) * 8]);
            else        a = *(const short8*)(&AG[lr * 64 + (((ks - 2) * 4 + lk) ^ (lr & 7)) * 8]);
#pragma unroll
            for (int n4 = 0; n4 < 4; ++n4) {
                int nt = wave * 4 + n4;
                short8 bb = *(const short8*)(WTu0 + (nt * 16 + lr) * 128 + ks * 32 + lk * 8);
                acc[n4] = mfma_bf16(a, bb, acc[n4]);
            }
        }
#pragma unroll
        for (int n4 = 0; n4 < 4; ++n4) {
            int col = (wave * 4 + n4) * 16 + lr;
            float bias = bu0[col];
#pragma unroll
            for (int j = 0; j < 4; ++j) {
                int lrow = lk * 4 + j;
                float v = gelu_f(acc[n4][j] + bias);
                H[lrow * 128 + ((col >> 3) ^ lrow) * 8 + (col & 7)] = f2bf(v);
            }
        }
    }
    __syncthreads();
    // ---- stage 3: GEMM4 split (2 nt each); residual into VF f32 ----
    if (wave < 2) {
        f32x4 acc2[2];
#pragma unroll
        for (int n2 = 0; n2 < 2; ++n2) acc2[n2] = (f32x4){0.f, 0.f, 0.f, 0.f};
#pragma unroll
        for (int ks = 0; ks < 4; ++ks) {
            short8 a = *(const short8*)(&H[lr * 128 + ((ks * 4 + lk) ^ lr) * 8]);
#pragma unroll
            for (int n2 = 0; n2 < 2; ++n2) {
                int nt = wave * 2 + n2;
                short8 bb = *(const short8*)(WTu1 + (nt * 16 + lr) * 128 + ks * 32 + lk * 8);
                acc2[n2] = mfma_bf16(a, bb, acc2[n2]);
            }
        }
#pragma unroll
        for (int n2 = 0; n2 < 2; ++n2) {
            int col = (wave * 2 + n2) * 16 + lr;
            float bias = bu1[col];
#pragma unroll
            for (int j = 0; j < 4; ++j) {
                int row = lk * 4 + j;
                float x = bf2f(X[row * 64 + ((col >> 3) ^ (row & 7)) * 8 + (col & 7)]);
                VF[row * 65 + col] = x + acc2[n2][j] + bias;
            }
        }
    }
    __syncthreads();
    // ---- stage 4: LN on wave 0 (reads VF) -> nodes_out + XO ----
    if (wave == 0) {
        float vals[4][4];
#pragma unroll
        for (int j = 0; j < 4; ++j) {
            int row = lk * 4 + j;
#pragma unroll
            for (int nt = 0; nt < 4; ++nt)
                vals[j][nt] = VF[row * 65 + nt * 16 + lr];
        }
#pragma unroll
        for (int j = 0; j < 4; ++j) {
            int row = lk * 4 + j;
            float s = vals[j][0] + vals[j][1] + vals[j][2] + vals[j][3];
#pragma unroll
            for (int mm = 1; mm < 16; mm <<= 1) s += __shfl_xor(s, mm, 64);
            float mean = s * (1.0f / 64.0f);
            float vs = 0.0f;
#pragma unroll
            for (int nt = 0; nt < 4; ++nt) { float d = vals[j][nt] - mean; vs += d * d; }
#pragma unroll
            for (int mm = 1; mm < 16; mm <<= 1) vs += __shfl_xor(vs, mm, 64);
            float inv = rsqrtf(vs * (1.0f / 64.0f) + 1e-6f);
#pragma unroll
            for (int nt = 0; nt < 4; ++nt) {
                int col = nt * 16 + lr;
                float o = (vals[j][nt] - mean) * inv * lng[col] + lnb[col];
                unsigned short ob = f2bf(o);
                nodes_out[((size_t)(n0 + row)) * 64 + col] = ob;
                XO[row * 64 + ((col >> 3) ^ (row & 7)) * 8 + (col & 7)] = ob;
            }
        }
    }
    __syncthreads();
    // ---- stage 5: wave 1 -> next-P; wave 0 -> head (concurrent) ----
    if (doP && wave == 1) {
        f32x4 accP[8];
#pragma unroll
        for (int nt = 0; nt < 8; ++nt) accP[nt] = (f32x4){0.f, 0.f, 0.f, 0.f};
#pragma unroll
        for (int ks = 0; ks < 2; ++ks) {
            short8 aa = *(const short8*)(&XO[lr * 64 + ((ks * 4 + lk) ^ (lr & 7)) * 8]);
#pragma unroll
            for (int nt = 0; nt < 8; ++nt) {
                short8 bb = *(const short8*)(Wm0n + (nt * 16 + lr) * 64 + ks * 32 + lk * 8);
                accP[nt] = mfma_bf16(aa, bb, accP[nt]);
            }
        }
#pragma unroll
        for (int j = 0; j < 4; ++j) {
            int node = n0 + lk * 4 + j;
            short8 ps;
#pragma unroll
            for (int nt = 0; nt < 8; ++nt) ps[nt] = (short)f2bf(accP[nt][j]);
            *(short8*)(Pout + (size_t)node * 128 + lr * 8) = ps;
        }
    }
    if (doHead && wave == 0) {
        int nloc = n0 % NN;
        int bq = n0 / NN;
#pragma unroll
        for (int half = 0; half < 2; ++half) {
            f32x4 ah[8];
#pragma unroll
            for (int nt = 0; nt < 8; ++nt) ah[nt] = (f32x4){0.f, 0.f, 0.f, 0.f};
#pragma unroll
            for (int ks = 0; ks < 2; ++ks) {
                short8 aa = *(const short8*)(&XO[lr * 64 + ((ks * 4 + lk) ^ (lr & 7)) * 8]);
#pragma unroll
                for (int nt = 0; nt < 8; ++nt) {
                    int col16 = half * 8 + nt;
                    short8 bb = *(const short8*)(wth0 + (col16 * 16 + lr) * 64 + ks * 32 + lk * 8);
                    ah[nt] = mfma_bf16(aa, bb, ah[nt]);
                }
            }
#pragma unroll
            for (int nt = 0; nt < 8; ++nt) {
                int col = (half * 8 + nt) * 16 + lr;
                float bias = hb0[col];
                int u = col >> 3;
#pragma unroll
                for (int j = 0; j < 4; ++j) {
                    int row = lk * 4 + j;
                    float v = gelu_f(ah[nt][j] + bias);
                    int us = (u & 16) | ((u ^ row) & 15);
                    HH[row * 256 + us * 8 + (col & 7)] = f2bf(v);
                }
            }
        }
        f32x4 a1h[4];
#pragma unroll
        for (int nt = 0; nt < 4; ++nt) a1h[nt] = (f32x4){0.f, 0.f, 0.f, 0.f};
#pragma unroll
        for (int ks = 0; ks < 8; ++ks) {
            int u = ks * 4 + lk;
            int us = (u & 16) | ((u ^ lr) & 15);
            short8 aa = *(const short8*)(&HH[lr * 256 + us * 8]);
#pragma unroll
            for (int nt = 0; nt < 4; ++nt) {
                short8 bb = *(const short8*)(wth1 + (nt * 16 + lr) * 256 + ks * 32 + lk * 8);
                a1h[nt] = mfma_bf16(aa, bb, a1h[nt]);
            }
        }
#pragma unroll
        for (int nt = 0; nt < 4; ++nt) {
            int col = nt * 16 + lr;
            float bias = hb1[col];
#pragma unroll
            for (int j = 0; j < 4; ++j) {
                int row = lk * 4 + j;
                HH1[row * 72 + col] = f2bf(gelu_f(a1h[nt][j] + bias));
            }
        }
        int task = lane >> 1;
        int row = task >> 1;
        int o = task & 1;
        int t2 = lane & 1;
        float pp = 0.0f;
#pragma unroll
        for (int d = 0; d < 32; ++d) {
            int dd = t2 * 32 + d;
            pp += bf2f(HH1[row * 72 + dd]) * hW2[dd * 2 + o];
        }
        pp += __shfl_xor(pp, 1, 64);
        if (t2 == 0) {
            int gg = bq * NT + (nloc - NC) + row;
            if (o == 0) out[gg] = pp + hb2[0];
            else        out[BB * NT + gg] = __expf(0.5f * (pp + hb2[1]));
        }
    }
}

extern "C" void kernel_launch(void* const* d_in, const int* in_sizes, int n_in,
                              void* d_out, int out_size, void* d_ws, size_t ws_size,
                              hipStream_t stream)
{
    (void)in_sizes; (void)n_in; (void)out_size; (void)ws_size;
    const float* s_ctx   = (const float*)d_in[0];
    const float* f_ctx   = (const float*)d_in[1];
    const float* s_test  = (const float*)d_in[2];
    const int*   valid   = (const int*)d_in[3];
    const float* emb_obs = (const float*)d_in[4];
    const float* ea_W0   = (const float*)d_in[5];
    const float* ea_b0   = (const float*)d_in[6];
    const float* ea_W1   = (const float*)d_in[7];
    const float* ea_b1   = (const float*)d_in[8];
    const float* ea_W2   = (const float*)d_in[9];
    const float* ea_b2   = (const float*)d_in[10];
    const float* ln_g    = (const float*)d_in[11];
    const float* ln_b    = (const float*)d_in[12];
    const float* blk_Wm0 = (const float*)d_in[13];
    const float* blk_bm0 = (const float*)d_in[14];
    const float* blk_Wm1 = (const float*)d_in[15];
    const float* blk_bm1 = (const float*)d_in[16];
    const float* blk_Wu0 = (const float*)d_in[17];
    const float* blk_bu0 = (const float*)d_in[18];
    const float* blk_Wu1 = (const float*)d_in[19];
    const float* blk_bu1 = (const float*)d_in[20];
    const float* blk_lng = (const float*)d_in[21];
    const float* blk_lnb = (const float*)d_in[22];
    const float* hd_W0   = (const float*)d_in[23];
    const float* hd_b0   = (const float*)d_in[24];
    const float* hd_W1   = (const float*)d_in[25];
    const float* hd_b1   = (const float*)d_in[26];
    const float* hd_W2   = (const float*)d_in[27];
    const float* hd_b2   = (const float*)d_in[28];

    char* p = (char*)d_ws;
    auto alloc = [&](size_t bytes) { char* r = p; p += (bytes + 255) & ~(size_t)255; return r; };
    unsigned short* nodesA = (unsigned short*)alloc((size_t)NODES * 64 * 2);
    unsigned short* nodesB = (unsigned short*)alloc((size_t)NODES * 64 * 2);
    unsigned short* PA     = (unsigned short*)alloc((size_t)NODES * 128 * 2);
    unsigned short* PB     = (unsigned short*)alloc((size_t)NODES * 128 * 2);
    float* dists   = (float*)alloc((size_t)NODES * KNN * 4);
    float* wbuf    = (float*)alloc((size_t)NODES * KNN * 4);
    int*   senders = (int*)alloc((size_t)NODES * KNN * 4);
    unsigned short* wtm0  = (unsigned short*)alloc((size_t)6 * 8192 * 2);
    unsigned short* wtm1p = (unsigned short*)alloc((size_t)6 * 8192 * 2);
    unsigned short* wtu0  = (unsigned short*)alloc((size_t)6 * 16384 * 2);
    unsigned short* wtu1  = (unsigned short*)alloc((size_t)6 * 8192 * 2);
    float* wdp  = (float*)alloc((size_t)6 * 128 * 4);
    float* bm0p = (float*)alloc((size_t)6 * 128 * 4);
    unsigned short* wte0 = (unsigned short*)alloc((size_t)8192 * 2);
    unsigned short* wte1 = (unsigned short*)alloc((size_t)32768 * 2);
    unsigned short* wte2 = (unsigned short*)alloc((size_t)8192 * 2);
    unsigned short* wth0 = (unsigned short*)alloc((size_t)16384 * 2);
    unsigned short* wth1 = (unsigned short*)alloc((size_t)16384 * 2);
    float4* s4 = (float4*)alloc((size_t)BB * NC * 16);

    k_convw<<<1350, 256, 0, stream>>>(
        blk_Wm0, blk_Wm1, blk_Wu0, blk_Wu1, blk_bm0,
        ea_W0, ea_W1, ea_W2, hd_W0, hd_W1, s_ctx, valid,
        wtm0, wtm1p, wtu0, wtu1, wdp, bm0p, wte0, wte1, wte2, wth0, wth1, s4);

    k_embed2<<<NODES / 64, 256, 0, stream>>>(s_ctx, f_ctx, s_test, emb_obs,
        wte0, ea_b0, wte1, ea_b1, wte2, ea_b2, ln_g, ln_b, wtm0, nodesA, PA);

    k_topk<<<NODES / 16, 256, 0, stream>>>(s4, s_ctx, s_test,
                                           dists, senders, wbuf);

    unsigned short* nin = nodesA; unsigned short* nout = nodesB;
    unsigned short* pin = PA;     unsigned short* pout = PB;
    for (int i = 0; i < NBLK; ++i) {
        int doP = (i < NBLK - 1) ? 1 : 0;
        int doHead = (i == NBLK - 1) ? 1 : 0;
        int testOnly = doHead;
        int grid = testOnly ? (BB * NT / 16) : (NODES / 16);
        const unsigned short* wm0n = wtm0 + (size_t)((i + 1) % NBLK) * 8192;
        k_blk<<<grid, 256, 0, stream>>>(nin, pin, dists, senders, wbuf,
            wdp + (size_t)i * 128, bm0p + (size_t)i * 128,
            wtm1p + (size_t)i * 8192, blk_bm1 + (size_t)i * 64,
            wtu0 + (size_t)i * 16384, blk_bu0 + (size_t)i * 128,
            wtu1 + (size_t)i * 8192, blk_bu1 + (size_t)i * 64,
            blk_lng + (size_t)i * 64, blk_lnb + (size_t)i * 64,
            wm0n, doP, nout, pout,
            doHead, testOnly, wth0, hd_b0, wth1, hd_b1, hd_W2, hd_b2, (float*)d_out);
        unsigned short* tmp = nin; nin = nout; nout = tmp;
        tmp = pin; pin = pout; pout = tmp;
    }
}

// Round 16
// 248.185 us; speedup vs baseline: 1.2415x; 1.0779x over previous
//
#include <hip/hip_runtime.h>
#include <math.h>

#define BB 4
#define NC 4096
#define NT 1024
#define NN (NC + NT)      // 5120
#define NODES (BB * NN)   // 20480
#define DD 64
#define KNN 10
#define NBLK 6
#define BIGF 3.0e38f
#define LM 5              // per-lane kept candidates (union covers global top-10, p_fail ~ 2e-7)

typedef __attribute__((ext_vector_type(8))) short short8;
typedef __attribute__((ext_vector_type(4))) float f32x4;
typedef __attribute__((ext_vector_type(4))) int int4v;

__device__ __forceinline__ unsigned short f2bf(float f) {
    unsigned int u = __float_as_uint(f);
    unsigned int r = (u + 0x7fffu + ((u >> 16) & 1u)) >> 16;
    return (unsigned short)r;
}
__device__ __forceinline__ float bf2f(unsigned short h) {
    return __uint_as_float(((unsigned int)h) << 16);
}

__device__ __forceinline__ float gelu_f(float x) {
    const float c0 = 0.7978845608028654f;
    float x3 = x * x * x;
    float z2 = 2.0f * c0 * (x + 0.044715f * x3);
    float e = __expf(z2);
    float r = __builtin_amdgcn_rcpf(1.0f + e);
    return x - x * r;
}

__device__ __forceinline__ float wave_sum(float v) {
#pragma unroll
    for (int off = 32; off > 0; off >>= 1) v += __shfl_xor(v, off, 64);
    return v;
}

__device__ __forceinline__ f32x4 mfma_bf16(short8 a, short8 b, f32x4 c) {
    asm("v_mfma_f32_16x16x32_bf16 %0, %1, %2, %0" : "+v"(c) : "v"(a), "v"(b));
    return c;
}

// perm(col) = (col&15)*8 + (col>>4); invperm(cp) = ((cp&7)<<4) | (cp>>3)

// ---------------- weight convert + masked s4 pack ----------------
__global__ __launch_bounds__(256) void k_convw(
    const float* __restrict__ Wm0, const float* __restrict__ Wm1,
    const float* __restrict__ Wu0, const float* __restrict__ Wu1,
    const float* __restrict__ bm0,
    const float* __restrict__ eW0, const float* __restrict__ eW1,
    const float* __restrict__ eW2,
    const float* __restrict__ hW0, const float* __restrict__ hW1,
    const float* __restrict__ sctx, const int* __restrict__ valid_lens,
    unsigned short* __restrict__ wtm0, unsigned short* __restrict__ wtm1p,
    unsigned short* __restrict__ wtu0, unsigned short* __restrict__ wtu1,
    float* __restrict__ wdp, float* __restrict__ bm0p,
    unsigned short* __restrict__ wte0, unsigned short* __restrict__ wte1,
    unsigned short* __restrict__ wte2,
    unsigned short* __restrict__ wth0, unsigned short* __restrict__ wth1,
    float4* __restrict__ s4)
{
    int t = blockIdx.x * 256 + threadIdx.x;
    if (t < 49152) {                 // wtm0 [6][128][64]
        int i = t / 8192, r = t % 8192, n = r / 64, k = r % 64;
        wtm0[t] = f2bf(Wm0[(i * 65 + k) * 128 + n]);
    } else if (t < 98304) {          // wtm1p [6][64][128]
        int u = t - 49152;
        int i = u / 8192, r = u % 8192, n = r / 128, cp = r % 128;
        int col = ((cp & 7) << 4) | (cp >> 3);
        wtm1p[u] = f2bf(Wm1[(i * 128 + col) * 64 + n]);
    } else if (t < 196608) {         // wtu0 [6][128][128]
        int u = t - 98304;
        int i = u / 16384, r = u % 16384, n = r / 128, k = r % 128;
        wtu0[u] = f2bf(Wu0[(i * 128 + k) * 128 + n]);
    } else if (t < 245760) {         // wtu1 [6][64][128]
        int u = t - 196608;
        int i = u / 8192, r = u % 8192, n = r / 128, k = r % 128;
        wtu1[u] = f2bf(Wu1[(i * 128 + k) * 64 + n]);
    } else if (t < 246528) {         // wdp [6][128] perm
        int u = t - 245760;
        int i = u / 128, cp = u % 128;
        int col = ((cp & 7) << 4) | (cp >> 3);
        wdp[u] = Wm0[(i * 65 + 64) * 128 + col];
    } else if (t < 247296) {         // bm0p [6][128] perm
        int u = t - 246528;
        int i = u / 128, cp = u % 128;
        int col = ((cp & 7) << 4) | (cp >> 3);
        bm0p[u] = bm0[i * 128 + col];
    } else if (t < 255488) {         // wte0 [256][32]
        int u = t - 247296;
        int n = u / 32, k = u % 32;
        wte0[u] = (k < 11) ? f2bf(eW0[k * 256 + n]) : 0;
    } else if (t < 288256) {         // wte1 [128][256]
        int u = t - 255488;
        int n = u / 256, k = u % 256;
        wte1[u] = f2bf(eW1[k * 128 + n]);
    } else if (t < 296448) {         // wte2 [64][128]
        int u = t - 288256;
        int n = u / 128, k = u % 128;
        wte2[u] = f2bf(eW2[k * 64 + n]);
    } else if (t < 312832) {         // wth0 [256][64]
        int u = t - 296448;
        int n = u / 64, k = u % 64;
        wth0[u] = f2bf(hW0[k * 256 + n]);
    } else if (t < 329216) {         // wth1 [64][256]
        int u = t - 312832;
        int n = u / 256, k = u % 256;
        wth1[u] = f2bf(hW1[k * 64 + n]);
    } else if (t < 329216 + BB * NC) {  // s4 pack with baked validity mask
        int u = t - 329216;
        int b = u / NC, j = u % NC;
        bool ok = j < valid_lens[b];
        float x = ok ? sctx[u * 3] : 1.0e6f;
        float y = ok ? sctx[u * 3 + 1] : 1.0e6f;
        float z = ok ? sctx[u * 3 + 2] : 1.0e6f;
        s4[u] = make_float4(x, y, z, 0.0f);
    }
}

// ---------------- embed (MFMA) + P0: 16 nodes per 1-wave block (balanced 5/CU) ----------------
__global__ __launch_bounds__(64) void k_embed2(
    const float* __restrict__ s_ctx, const float* __restrict__ f_ctx,
    const float* __restrict__ s_test, const float* __restrict__ emb_obs,
    const unsigned short* __restrict__ WT0, const float* __restrict__ b0,
    const unsigned short* __restrict__ WT1, const float* __restrict__ b1,
    const unsigned short* __restrict__ WT2, const float* __restrict__ b2,
    const float* __restrict__ g, const float* __restrict__ bta,
    const unsigned short* __restrict__ Wm0n,     // [128][64] (block 0)
    unsigned short* __restrict__ nodes,
    unsigned short* __restrict__ Pout)           // bf16 [NODES][128] perm
{
    __shared__ unsigned short h0[16 * 256];
    __shared__ unsigned short h1[16 * 128];
    __shared__ unsigned short xo[16 * 64];
    int lane = threadIdx.x & 63, lr = lane & 15, lk = lane >> 4;
    int n0 = blockIdx.x * 16;
    int bq = n0 / NN, nloc0 = n0 % NN;
    bool is_ctx = nloc0 < NC;
    int nr = nloc0 + lr;
    float xv[8];
#pragma unroll
    for (int j = 0; j < 8; ++j) xv[j] = 0.0f;
    if (lk == 0) {
        const float* eb = emb_obs + (is_ctx ? 4 : 0);
        xv[0] = eb[0]; xv[1] = eb[1]; xv[2] = eb[2]; xv[3] = eb[3];
        if (is_ctx) {
            const float* sp = s_ctx + ((size_t)(bq * NC + nr)) * 3;
            const float* fp = f_ctx + ((size_t)(bq * NC + nr)) * 4;
            xv[4] = sp[0]; xv[5] = sp[1]; xv[6] = sp[2]; xv[7] = fp[0];
        } else {
            const float* sp = s_test + ((size_t)(bq * NT + nr - NC)) * 3;
            xv[4] = sp[0]; xv[5] = sp[1]; xv[6] = sp[2];
        }
    } else if (lk == 1 && is_ctx) {
        const float* fp = f_ctx + ((size_t)(bq * NC + nr)) * 4;
        xv[0] = fp[1]; xv[1] = fp[2]; xv[2] = fp[3];
    }
    short8 a;
#pragma unroll
    for (int j = 0; j < 8; ++j) a[j] = (short)f2bf(xv[j]);

    f32x4 acc0[16];
#pragma unroll
    for (int nt = 0; nt < 16; ++nt) {
        short8 bb = *(const short8*)(WT0 + (nt * 16 + lr) * 32 + lk * 8);
        f32x4 z = (f32x4){0.f, 0.f, 0.f, 0.f};
        acc0[nt] = mfma_bf16(a, bb, z);
    }
#pragma unroll
    for (int nt = 0; nt < 16; ++nt) {
        int col = nt * 16 + lr;
        float bias = b0[col];
        int u = col >> 3;
#pragma unroll
        for (int j = 0; j < 4; ++j) {
            int row = lk * 4 + j;
            float v = gelu_f(acc0[nt][j] + bias);
            int us = (u & 16) | ((u ^ row) & 15);
            h0[row * 256 + us * 8 + (col & 7)] = f2bf(v);
        }
    }
    f32x4 acc1[8];
#pragma unroll
    for (int nt = 0; nt < 8; ++nt) acc1[nt] = (f32x4){0.f, 0.f, 0.f, 0.f};
#pragma unroll
    for (int ks = 0; ks < 8; ++ks) {
        int u = ks * 4 + lk;
        int us = (u & 16) | ((u ^ lr) & 15);
        short8 aa = *(const short8*)(&h0[lr * 256 + us * 8]);
#pragma unroll
        for (int nt = 0; nt < 8; ++nt) {
            short8 bb = *(const short8*)(WT1 + (nt * 16 + lr) * 256 + ks * 32 + lk * 8);
            acc1[nt] = mfma_bf16(aa, bb, acc1[nt]);
        }
    }
#pragma unroll
    for (int nt = 0; nt < 8; ++nt) {
        int col = nt * 16 + lr;
        float bias = b1[col];
        int u = col >> 3;
#pragma unroll
        for (int j = 0; j < 4; ++j) {
            int row = lk * 4 + j;
            float v = gelu_f(acc1[nt][j] + bias);
            int us = (u ^ row) & 15;
            h1[row * 128 + us * 8 + (col & 7)] = f2bf(v);
        }
    }
    f32x4 acc2[4];
#pragma unroll
    for (int nt = 0; nt < 4; ++nt) acc2[nt] = (f32x4){0.f, 0.f, 0.f, 0.f};
#pragma unroll
    for (int ks = 0; ks < 4; ++ks) {
        int u = ks * 4 + lk;
        int us = (u ^ lr) & 15;
        short8 aa = *(const short8*)(&h1[lr * 128 + us * 8]);
#pragma unroll
        for (int nt = 0; nt < 4; ++nt) {
            short8 bb = *(const short8*)(WT2 + (nt * 16 + lr) * 128 + ks * 32 + lk * 8);
            acc2[nt] = mfma_bf16(aa, bb, acc2[nt]);
        }
    }
    float vals[4][4];
#pragma unroll
    for (int j = 0; j < 4; ++j)
#pragma unroll
        for (int nt = 0; nt < 4; ++nt)
            vals[j][nt] = acc2[nt][j] + b2[nt * 16 + lr];
#pragma unroll
    for (int j = 0; j < 4; ++j) {
        float s = vals[j][0] + vals[j][1] + vals[j][2] + vals[j][3];
#pragma unroll
        for (int m = 1; m < 16; m <<= 1) s += __shfl_xor(s, m, 64);
        float mean = s * (1.0f / 64.0f);
        float vs = 0.0f;
#pragma unroll
        for (int nt = 0; nt < 4; ++nt) { float d = vals[j][nt] - mean; vs += d * d; }
#pragma unroll
        for (int m = 1; m < 16; m <<= 1) vs += __shfl_xor(vs, m, 64);
        float inv = rsqrtf(vs * (1.0f / 64.0f) + 1e-6f);
        int row = lk * 4 + j;
        int node = n0 + row;
#pragma unroll
        for (int nt = 0; nt < 4; ++nt) {
            int col = nt * 16 + lr;
            float o = (vals[j][nt] - mean) * inv * g[col] + bta[col];
            unsigned short ob = f2bf(o);
            nodes[(size_t)node * 64 + col] = ob;
            xo[row * 64 + ((col >> 3) ^ (row & 7)) * 8 + (col & 7)] = ob;
        }
    }
    // P0 = ln_out @ Wm0[0][0:64]
    f32x4 accP[8];
#pragma unroll
    for (int nt = 0; nt < 8; ++nt) accP[nt] = (f32x4){0.f, 0.f, 0.f, 0.f};
#pragma unroll
    for (int ks = 0; ks < 2; ++ks) {
        short8 aa = *(const short8*)(&xo[lr * 64 + ((ks * 4 + lk) ^ (lr & 7)) * 8]);
#pragma unroll
        for (int nt = 0; nt < 8; ++nt) {
            short8 bb = *(const short8*)(Wm0n + (nt * 16 + lr) * 64 + ks * 32 + lk * 8);
            accP[nt] = mfma_bf16(aa, bb, accP[nt]);
        }
    }
#pragma unroll
    for (int j = 0; j < 4; ++j) {
        int node = n0 + lk * 4 + j;
        short8 ps;
#pragma unroll
        for (int nt = 0; nt < 8; ++nt) ps[nt] = (short)f2bf(accP[nt][j]);
        *(short8*)(Pout + (size_t)node * 128 + lr * 8) = ps;
    }
}

// ---------------- top-K: per-lane top-5 med3 + LDS-atomic collection passB ----------------
__global__ __launch_bounds__(256) void k_topk(
    const float4* __restrict__ s4, const float* __restrict__ s_ctx,
    const float* __restrict__ s_test,
    float* __restrict__ dists, int* __restrict__ senders, float* __restrict__ wout)
{
    __shared__ float cd[4 * 64 * 11];
    __shared__ float slotv[4][4][16];
    __shared__ int   sloti[4][4][16];
    __shared__ int   cnt[4][4];
    int wave = threadIdx.x >> 6;
    int lane = threadIdx.x & 63;
    int r0 = blockIdx.x * 16 + wave * 4;
    int b = r0 / NN;
    const float4* sc = s4 + (size_t)b * NC;
    float px[4], py[4], pz[4];
#pragma unroll
    for (int q = 0; q < 4; ++q) {
        int n = (r0 + q) % NN;
        const float* p = (n < NC) ? &s_ctx[(size_t)(b * NC + n) * 3]
                                  : &s_test[(size_t)(b * NT + (n - NC)) * 3];
        px[q] = p[0]; py[q] = p[1]; pz[q] = p[2];
    }
    float bq[4][LM];
#pragma unroll
    for (int q = 0; q < 4; ++q)
#pragma unroll
        for (int k = 0; k < LM; ++k) bq[q][k] = BIGF;
#pragma unroll 8
    for (int i = 0; i < 64; ++i) {
        int j = lane + (i << 6);
        float4 s = sc[j];
#pragma unroll
        for (int q = 0; q < 4; ++q) {
            float dx = px[q] - s.x, dy = py[q] - s.y, dz = pz[q] - s.z;
            float d2 = fmaf(dx, dx, fmaf(dy, dy, dz * dz));
#pragma unroll
            for (int k = LM - 1; k >= 1; --k)
                bq[q][k] = __builtin_amdgcn_fmed3f(bq[q][k - 1], bq[q][k], d2);
            bq[q][0] = fminf(bq[q][0], d2);
        }
    }
    int base = (wave * 64 + lane) * 11;
    float T[4];
#pragma unroll
    for (int q = 0; q < 4; ++q) {
#pragma unroll
        for (int k = 0; k < LM; ++k) cd[base + k] = bq[q][k];
        cd[base + LM] = BIGF;
        __builtin_amdgcn_wave_barrier();
        int head = 0;
        float Tl = BIGF;
#pragma unroll
        for (int rr = 0; rr < KNN; ++rr) {
            float v = cd[base + head];
            float mv = v;
#pragma unroll
            for (int off = 32; off > 0; off >>= 1) mv = fminf(mv, __shfl_xor(mv, off, 64));
            unsigned long long ball = __ballot(v == mv);
            int win = __ffsll(ball) - 1;
            if (lane == win) head++;
            Tl = mv;
        }
        T[q] = Tl;
    }
    if (lane < 4) cnt[wave][lane] = 0;
    __builtin_amdgcn_wave_barrier();
#pragma unroll 4
    for (int i = 0; i < 64; ++i) {
        int j = lane + (i << 6);
        float4 s = sc[j];
#pragma unroll
        for (int q = 0; q < 4; ++q) {
            float dx = px[q] - s.x, dy = py[q] - s.y, dz = pz[q] - s.z;
            float v = fmaf(dx, dx, fmaf(dy, dy, dz * dz));
            if (v <= T[q]) {
                int slot = atomicAdd(&cnt[wave][q], 1);
                if (slot < 16) { slotv[wave][q][slot] = v; sloti[wave][q][slot] = j; }
            }
        }
    }
    __builtin_amdgcn_wave_barrier();
#pragma unroll
    for (int q = 0; q < 4; ++q) {
        int count = cnt[wave][q];
        if (count > 16) count = 16;
        float e = 0.0f, d = 0.0f;
        int isel = 0, rank = 0;
        bool own = lane < count;
        if (own) {
            float myv = slotv[wave][q][lane];
            int myi = sloti[wave][q][lane];
            for (int j = 0; j < count; ++j) {
                float vj = slotv[wave][q][j];
                int ij = sloti[wave][q][j];
                rank += (vj < myv || (vj == myv && ij < myi)) ? 1 : 0;
            }
            own = rank < KNN;
            if (own) {
                isel = myi;
                d = sqrtf(myv);
                e = __expf(-d);
            }
        }
        float ssum = wave_sum(e);
        if (own) {
            size_t o = (size_t)(r0 + q) * KNN + rank;
            dists[o] = d;
            senders[o] = isel;
            wout[o] = e / ssum;
        }
    }
}

// ---------------- fused block: 4-wave gather + 4-wave split GEMM tail (+head on last) ----------------
// 16 nodes per 256-thread block; XCD-swizzled tiles; last iteration: test tiles only
__global__ __launch_bounds__(256) void k_blk(
    const unsigned short* __restrict__ nodes_in,
    const unsigned short* __restrict__ P,        // bf16 [NODES][128] perm (read)
    const float* __restrict__ dists, const int* __restrict__ senders,
    const float* __restrict__ w,
    const float* __restrict__ wdp, const float* __restrict__ bm0p,
    const unsigned short* __restrict__ Wm1p,     // [64][128] (perm k)
    const float* __restrict__ bm1,
    const unsigned short* __restrict__ WTu0,     // [128][128]
    const float* __restrict__ bu0,
    const unsigned short* __restrict__ WTu1,     // [64][128]
    const float* __restrict__ bu1,
    const float* __restrict__ lng, const float* __restrict__ lnb,
    const unsigned short* __restrict__ Wm0n,     // [128][64] next-iter
    const int doP,
    unsigned short* __restrict__ nodes_out,
    unsigned short* __restrict__ Pout,           // ping-pong buffer
    const int doHead, const int testOnly,
    const unsigned short* __restrict__ wth0,     // [256][64]
    const float* __restrict__ hb0,
    const unsigned short* __restrict__ wth1,     // [64][256]
    const float* __restrict__ hb1,
    const float* __restrict__ hW2, const float* __restrict__ hb2,
    float* __restrict__ out)
{
    __shared__ unsigned short X[16 * 64];
    __shared__ unsigned short G[16 * 128];
    __shared__ unsigned short AG[16 * 64];
    __shared__ unsigned short H[16 * 128];
    __shared__ unsigned short XO[16 * 64];
    __shared__ float VF[16 * 65];                // f32 staging for split LN
    __shared__ unsigned short HH[16 * 256];
    __shared__ unsigned short HH1[16 * 72];
    __shared__ int   sidE[160];
    __shared__ float dE[160], wE[160];
    int l = threadIdx.x;
    int wave = l >> 6, lane = l & 63;
    int bid = blockIdx.x;
    int tile = testOnly ? ((bid >> 6) * 320 + 256 + (bid & 63))
                        : ((bid & 7) * 160 + (bid >> 3));
    int n0 = tile * 16;
    int b = n0 / NN;
    size_t bbase = (size_t)b * NN;
    int e0 = n0 * KNN;
    if (l < 160) {
        sidE[l] = senders[e0 + l];
        dE[l]   = dists[e0 + l];
        wE[l]   = w[e0 + l];
    }
    if (l < 128) {
        int row = l >> 3, u = l & 7;
        int4v v = *(const int4v*)(nodes_in + ((size_t)(n0 + row)) * 64 + u * 8);
        *(int4v*)(&X[row * 64 + (u ^ (row & 7)) * 8]) = v;
    }
    __syncthreads();
    // gather + gelu + weighted sum -> G; wave w handles nodes w*4 .. w*4+3
    float wd0 = wdp[2 * lane], wd1 = wdp[2 * lane + 1];
    float bb0 = bm0p[2 * lane], bb1 = bm0p[2 * lane + 1];
    const unsigned int* Pb = (const unsigned int*)P;
    unsigned int* G32 = (unsigned int*)G;
#pragma unroll
    for (int nn = 0; nn < 4; ++nn) {
        int n = wave * 4 + nn;
        float a0 = 0.0f, a1 = 0.0f;
#pragma unroll
        for (int k = 0; k < KNN; ++k) {
            int e = n * KNN + k;
            int sid = sidE[e];
            float dd = dE[e], ww = wE[e];
            unsigned int pr = Pb[(bbase + sid) * 64 + lane];
            float p0 = __uint_as_float(pr << 16);
            float p1 = __uint_as_float(pr & 0xFFFF0000u);
            float g0 = gelu_f(fmaf(dd, wd0, p0 + bb0));
            float g1 = gelu_f(fmaf(dd, wd1, p1 + bb1));
            a0 = fmaf(ww, g0, a0);
            a1 = fmaf(ww, g1, a1);
        }
        unsigned int pk = (unsigned int)f2bf(a0) | ((unsigned int)f2bf(a1) << 16);
        G32[n * 64 + ((lane >> 2) ^ n) * 4 + (lane & 3)] = pk;
    }
    __syncthreads();
    int lr = lane & 15, lk = lane >> 4;
    // ---- stage 1: GEMM_A split across 4 waves (1 nt each) ----
    {
        f32x4 accA = (f32x4){0.f, 0.f, 0.f, 0.f};
        int nt = wave;
#pragma unroll
        for (int ks = 0; ks < 4; ++ks) {
            short8 a = *(const short8*)(&G[lr * 128 + ((ks * 4 + lk) ^ lr) * 8]);
            short8 bb = *(const short8*)(Wm1p + (nt * 16 + lr) * 128 + ks * 32 + lk * 8);
            accA = mfma_bf16(a, bb, accA);
        }
        int col = nt * 16 + lr;
        float bias = bm1[col];
#pragma unroll
        for (int j = 0; j < 4; ++j) {
            int row = lk * 4 + j;
            AG[row * 64 + ((col >> 3) ^ (row & 7)) * 8 + (col & 7)] =
                f2bf(accA[j] + bias);
        }
    }
    __syncthreads();
    // ---- stage 2: GEMM3 split across 4 waves (2 nt each) ----
    {
        f32x4 acc[2];
#pragma unroll
        for (int n2 = 0; n2 < 2; ++n2) acc[n2] = (f32x4){0.f, 0.f, 0.f, 0.f};
#pragma unroll
        for (int ks = 0; ks < 4; ++ks) {
            short8 a;
            if (ks < 2) a = *(const short8*)(&X[lr * 64 + ((ks * 4 + lk) ^ (lr & 7)) * 8]);
            else        a = *(const short8*)(&AG[lr * 64 + (((ks - 2) * 4 + lk) ^ (lr & 7)) * 8]);
#pragma unroll
            for (int n2 = 0; n2 < 2; ++n2) {
                int nt = wave * 2 + n2;
                short8 bb = *(const short8*)(WTu0 + (nt * 16 + lr) * 128 + ks * 32 + lk * 8);
                acc[n2] = mfma_bf16(a, bb, acc[n2]);
            }
        }
#pragma unroll
        for (int n2 = 0; n2 < 2; ++n2) {
            int col = (wave * 2 + n2) * 16 + lr;
            float bias = bu0[col];
#pragma unroll
            for (int j = 0; j < 4; ++j) {
                int lrow = lk * 4 + j;
                float v = gelu_f(acc[n2][j] + bias);
                H[lrow * 128 + ((col >> 3) ^ lrow) * 8 + (col & 7)] = f2bf(v);
            }
        }
    }
    __syncthreads();
    // ---- stage 3: GEMM4 split across 4 waves (1 nt each); residual into VF f32 ----
    {
        f32x4 acc2 = (f32x4){0.f, 0.f, 0.f, 0.f};
        int nt = wave;
#pragma unroll
        for (int ks = 0; ks < 4; ++ks) {
            short8 a = *(const short8*)(&H[lr * 128 + ((ks * 4 + lk) ^ lr) * 8]);
            short8 bb = *(const short8*)(WTu1 + (nt * 16 + lr) * 128 + ks * 32 + lk * 8);
            acc2 = mfma_bf16(a, bb, acc2);
        }
        int col = nt * 16 + lr;
        float bias = bu1[col];
#pragma unroll
        for (int j = 0; j < 4; ++j) {
            int row = lk * 4 + j;
            float x = bf2f(X[row * 64 + ((col >> 3) ^ (row & 7)) * 8 + (col & 7)]);
            VF[row * 65 + col] = x + acc2[j] + bias;
        }
    }
    __syncthreads();
    // ---- stage 4: LN on wave 0 (reads VF) -> nodes_out + XO ----
    if (wave == 0) {
        float vals[4][4];
#pragma unroll
        for (int j = 0; j < 4; ++j) {
            int row = lk * 4 + j;
#pragma unroll
            for (int nt = 0; nt < 4; ++nt)
                vals[j][nt] = VF[row * 65 + nt * 16 + lr];
        }
#pragma unroll
        for (int j = 0; j < 4; ++j) {
            int row = lk * 4 + j;
            float s = vals[j][0] + vals[j][1] + vals[j][2] + vals[j][3];
#pragma unroll
            for (int mm = 1; mm < 16; mm <<= 1) s += __shfl_xor(s, mm, 64);
            float mean = s * (1.0f / 64.0f);
            float vs = 0.0f;
#pragma unroll
            for (int nt = 0; nt < 4; ++nt) { float d = vals[j][nt] - mean; vs += d * d; }
#pragma unroll
            for (int mm = 1; mm < 16; mm <<= 1) vs += __shfl_xor(vs, mm, 64);
            float inv = rsqrtf(vs * (1.0f / 64.0f) + 1e-6f);
#pragma unroll
            for (int nt = 0; nt < 4; ++nt) {
                int col = nt * 16 + lr;
                float o = (vals[j][nt] - mean) * inv * lng[col] + lnb[col];
                unsigned short ob = f2bf(o);
                nodes_out[((size_t)(n0 + row)) * 64 + col] = ob;
                XO[row * 64 + ((col >> 3) ^ (row & 7)) * 8 + (col & 7)] = ob;
            }
        }
    }
    __syncthreads();
    // ---- stage 5: wave 1 -> next-P; wave 0 -> head (concurrent) ----
    if (doP && wave == 1) {
        f32x4 accP[8];
#pragma unroll
        for (int nt = 0; nt < 8; ++nt) accP[nt] = (f32x4){0.f, 0.f, 0.f, 0.f};
#pragma unroll
        for (int ks = 0; ks < 2; ++ks) {
            short8 aa = *(const short8*)(&XO[lr * 64 + ((ks * 4 + lk) ^ (lr & 7)) * 8]);
#pragma unroll
            for (int nt = 0; nt < 8; ++nt) {
                short8 bb = *(const short8*)(Wm0n + (nt * 16 + lr) * 64 + ks * 32 + lk * 8);
                accP[nt] = mfma_bf16(aa, bb, accP[nt]);
            }
        }
#pragma unroll
        for (int j = 0; j < 4; ++j) {
            int node = n0 + lk * 4 + j;
            short8 ps;
#pragma unroll
            for (int nt = 0; nt < 8; ++nt) ps[nt] = (short)f2bf(accP[nt][j]);
            *(short8*)(Pout + (size_t)node * 128 + lr * 8) = ps;
        }
    }
    if (doHead && wave == 0) {
        int nloc = n0 % NN;
        int bq = n0 / NN;
#pragma unroll
        for (int half = 0; half < 2; ++half) {
            f32x4 ah[8];
#pragma unroll
            for (int nt = 0; nt < 8; ++nt) ah[nt] = (f32x4){0.f, 0.f, 0.f, 0.f};
#pragma unroll
            for (int ks = 0; ks < 2; ++ks) {
                short8 aa = *(const short8*)(&XO[lr * 64 + ((ks * 4 + lk) ^ (lr & 7)) * 8]);
#pragma unroll
                for (int nt = 0; nt < 8; ++nt) {
                    int col16 = half * 8 + nt;
                    short8 bb = *(const short8*)(wth0 + (col16 * 16 + lr) * 64 + ks * 32 + lk * 8);
                    ah[nt] = mfma_bf16(aa, bb, ah[nt]);
                }
            }
#pragma unroll
            for (int nt = 0; nt < 8; ++nt) {
                int col = (half * 8 + nt) * 16 + lr;
                float bias = hb0[col];
                int u = col >> 3;
#pragma unroll
                for (int j = 0; j < 4; ++j) {
                    int row = lk * 4 + j;
                    float v = gelu_f(ah[nt][j] + bias);
                    int us = (u & 16) | ((u ^ row) & 15);
                    HH[row * 256 + us * 8 + (col & 7)] = f2bf(v);
                }
            }
        }
        f32x4 a1h[4];
#pragma unroll
        for (int nt = 0; nt < 4; ++nt) a1h[nt] = (f32x4){0.f, 0.f, 0.f, 0.f};
#pragma unroll
        for (int ks = 0; ks < 8; ++ks) {
            int u = ks * 4 + lk;
            int us = (u & 16) | ((u ^ lr) & 15);
            short8 aa = *(const short8*)(&HH[lr * 256 + us * 8]);
#pragma unroll
            for (int nt = 0; nt < 4; ++nt) {
                short8 bb = *(const short8*)(wth1 + (nt * 16 + lr) * 256 + ks * 32 + lk * 8);
                a1h[nt] = mfma_bf16(aa, bb, a1h[nt]);
            }
        }
#pragma unroll
        for (int nt = 0; nt < 4; ++nt) {
            int col = nt * 16 + lr;
            float bias = hb1[col];
#pragma unroll
            for (int j = 0; j < 4; ++j) {
                int row = lk * 4 + j;
                HH1[row * 72 + col] = f2bf(gelu_f(a1h[nt][j] + bias));
            }
        }
        int task = lane >> 1;
        int row = task >> 1;
        int o = task & 1;
        int t2 = lane & 1;
        float pp = 0.0f;
#pragma unroll
        for (int d = 0; d < 32; ++d) {
            int dd = t2 * 32 + d;
            pp += bf2f(HH1[row * 72 + dd]) * hW2[dd * 2 + o];
        }
        pp += __shfl_xor(pp, 1, 64);
        if (t2 == 0) {
            int gg = bq * NT + (nloc - NC) + row;
            if (o == 0) out[gg] = pp + hb2[0];
            else        out[BB * NT + gg] = __expf(0.5f * (pp + hb2[1]));
        }
    }
}

extern "C" void kernel_launch(void* const* d_in, const int* in_sizes, int n_in,
                              void* d_out, int out_size, void* d_ws, size_t ws_size,
                              hipStream_t stream)
{
    (void)in_sizes; (void)n_in; (void)out_size; (void)ws_size;
    const float* s_ctx   = (const float*)d_in[0];
    const float* f_ctx   = (const float*)d_in[1];
    const float* s_test  = (const float*)d_in[2];
    const int*   valid   = (const int*)d_in[3];
    const float* emb_obs = (const float*)d_in[4];
    const float* ea_W0   = (const float*)d_in[5];
    const float* ea_b0   = (const float*)d_in[6];
    const float* ea_W1   = (const float*)d_in[7];
    const float* ea_b1   = (const float*)d_in[8];
    const float* ea_W2   = (const float*)d_in[9];
    const float* ea_b2   = (const float*)d_in[10];
    const float* ln_g    = (const float*)d_in[11];
    const float* ln_b    = (const float*)d_in[12];
    const float* blk_Wm0 = (const float*)d_in[13];
    const float* blk_bm0 = (const float*)d_in[14];
    const float* blk_Wm1 = (const float*)d_in[15];
    const float* blk_bm1 = (const float*)d_in[16];
    const float* blk_Wu0 = (const float*)d_in[17];
    const float* blk_bu0 = (const float*)d_in[18];
    const float* blk_Wu1 = (const float*)d_in[19];
    const float* blk_bu1 = (const float*)d_in[20];
    const float* blk_lng = (const float*)d_in[21];
    const float* blk_lnb = (const float*)d_in[22];
    const float* hd_W0   = (const float*)d_in[23];
    const float* hd_b0   = (const float*)d_in[24];
    const float* hd_W1   = (const float*)d_in[25];
    const float* hd_b1   = (const float*)d_in[26];
    const float* hd_W2   = (const float*)d_in[27];
    const float* hd_b2   = (const float*)d_in[28];

    char* p = (char*)d_ws;
    auto alloc = [&](size_t bytes) { char* r = p; p += (bytes + 255) & ~(size_t)255; return r; };
    unsigned short* nodesA = (unsigned short*)alloc((size_t)NODES * 64 * 2);
    unsigned short* nodesB = (unsigned short*)alloc((size_t)NODES * 64 * 2);
    unsigned short* PA     = (unsigned short*)alloc((size_t)NODES * 128 * 2);
    unsigned short* PB     = (unsigned short*)alloc((size_t)NODES * 128 * 2);
    float* dists   = (float*)alloc((size_t)NODES * KNN * 4);
    float* wbuf    = (float*)alloc((size_t)NODES * KNN * 4);
    int*   senders = (int*)alloc((size_t)NODES * KNN * 4);
    unsigned short* wtm0  = (unsigned short*)alloc((size_t)6 * 8192 * 2);
    unsigned short* wtm1p = (unsigned short*)alloc((size_t)6 * 8192 * 2);
    unsigned short* wtu0  = (unsigned short*)alloc((size_t)6 * 16384 * 2);
    unsigned short* wtu1  = (unsigned short*)alloc((size_t)6 * 8192 * 2);
    float* wdp  = (float*)alloc((size_t)6 * 128 * 4);
    float* bm0p = (float*)alloc((size_t)6 * 128 * 4);
    unsigned short* wte0 = (unsigned short*)alloc((size_t)8192 * 2);
    unsigned short* wte1 = (unsigned short*)alloc((size_t)32768 * 2);
    unsigned short* wte2 = (unsigned short*)alloc((size_t)8192 * 2);
    unsigned short* wth0 = (unsigned short*)alloc((size_t)16384 * 2);
    unsigned short* wth1 = (unsigned short*)alloc((size_t)16384 * 2);
    float4* s4 = (float4*)alloc((size_t)BB * NC * 16);

    k_convw<<<1350, 256, 0, stream>>>(
        blk_Wm0, blk_Wm1, blk_Wu0, blk_Wu1, blk_bm0,
        ea_W0, ea_W1, ea_W2, hd_W0, hd_W1, s_ctx, valid,
        wtm0, wtm1p, wtu0, wtu1, wdp, bm0p, wte0, wte1, wte2, wth0, wth1, s4);

    k_embed2<<<NODES / 16, 64, 0, stream>>>(s_ctx, f_ctx, s_test, emb_obs,
        wte0, ea_b0, wte1, ea_b1, wte2, ea_b2, ln_g, ln_b, wtm0, nodesA, PA);

    k_topk<<<NODES / 16, 256, 0, stream>>>(s4, s_ctx, s_test,
                                           dists, senders, wbuf);

    unsigned short* nin = nodesA; unsigned short* nout = nodesB;
    unsigned short* pin = PA;     unsigned short* pout = PB;
    for (int i = 0; i < NBLK; ++i) {
        int doP = (i < NBLK - 1) ? 1 : 0;
        int doHead = (i == NBLK - 1) ? 1 : 0;
        int testOnly = doHead;
        int grid = testOnly ? (BB * NT / 16) : (NODES / 16);
        const unsigned short* wm0n = wtm0 + (size_t)((i + 1) % NBLK) * 8192;
        k_blk<<<grid, 256, 0, stream>>>(nin, pin, dists, senders, wbuf,
            wdp + (size_t)i * 128, bm0p + (size_t)i * 128,
            wtm1p + (size_t)i * 8192, blk_bm1 + (size_t)i * 64,
            wtu0 + (size_t)i * 16384, blk_bu0 + (size_t)i * 128,
            wtu1 + (size_t)i * 8192, blk_bu1 + (size_t)i * 64,
            blk_lng + (size_t)i * 64, blk_lnb + (size_t)i * 64,
            wm0n, doP, nout, pout,
            doHead, testOnly, wth0, hd_b0, wth1, hd_b1, hd_W2, hd_b2, (float*)d_out);
        unsigned short* tmp = nin; nin = nout; nout = tmp;
        tmp = pin; pin = pout; pout = tmp;
    }
}